// Round 8
// baseline (2140.127 us; speedup 1.0000x reference)
//
#include <hip/hip_runtime.h>

#define B_ 64
#define L_ 2048
#define D_ 128
#define LP 2056   // padded rows per batch (3 left, 5 right incl. alignment)
#define PAD 3     // SAME-pad left for W=8

typedef __attribute__((ext_vector_type(8))) short short8;
typedef __attribute__((ext_vector_type(4))) float f32x4;
typedef __attribute__((ext_vector_type(4))) unsigned short us4;

static __device__ __forceinline__ float bf2f(unsigned short u) {
  return __uint_as_float(((unsigned int)u) << 16);
}
static __device__ __forceinline__ unsigned short f2bf(float f) {
  unsigned int x = __float_as_uint(f);
  unsigned int r = (x + 0x7fffu + ((x >> 16) & 1u)) >> 16;  // RNE
  return (unsigned short)r;
}

// ---------------------------------------------------------------------------
// K0: gather tok -> bf16 padded [B,LP,128]; zero l1pad's pad rows; gather bias;
//     transpose weights to bf16 [n][k] layouts for MFMA B-fragments.
// ---------------------------------------------------------------------------
__global__ __launch_bounds__(256) void k_prep(
    const int* __restrict__ code, const float* __restrict__ E,
    const float* __restrict__ bias_table, const float* __restrict__ Wx,
    const float* __restrict__ c1w, const float* __restrict__ c2w,
    unsigned short* __restrict__ tokpad, unsigned short* __restrict__ l1pad,
    unsigned short* __restrict__ WxT, unsigned short* __restrict__ c1wT,
    unsigned short* __restrict__ c2wT, float* __restrict__ biasg)
{
  int id = blockIdx.x * 256 + threadIdx.x;
  const int N0 = B_ * LP * 16;            // tokpad in uint4 (8 bf16) chunks
  if (id < N0) {
    int b = id / (LP * 16); int rem = id % (LP * 16);
    int row = rem >> 4, c8 = rem & 15;
    uint4 o = {0u,0u,0u,0u};
    if (row >= PAD && row < PAD + L_) {
      int cd = code[b * L_ + (row - PAD)];
      const float4* e = (const float4*)(E + (size_t)cd * D_ + c8 * 8);
      float4 e0 = e[0], e1 = e[1];
      o.x = f2bf(e0.x) | ((unsigned int)f2bf(e0.y) << 16);
      o.y = f2bf(e0.z) | ((unsigned int)f2bf(e0.w) << 16);
      o.z = f2bf(e1.x) | ((unsigned int)f2bf(e1.y) << 16);
      o.w = f2bf(e1.z) | ((unsigned int)f2bf(e1.w) << 16);
    }
    ((uint4*)tokpad)[id] = o;
    return;
  }
  id -= N0;
  const int N1 = B_ * 8 * 8;              // l1pad pad rows (8 rows x 8 chunks)
  if (id < N1) {
    int b = id >> 6; int rem = id & 63; int ri = rem >> 3, c8 = rem & 7;
    int row = ri < 3 ? ri : (L_ + ri);    // 0,1,2, 2051..2055
    uint4 z = {0u,0u,0u,0u};
    ((uint4*)l1pad)[(b * LP + row) * 8 + c8] = z;
    return;
  }
  id -= N1;
  const int N2 = B_ * L_;
  if (id < N2) { biasg[id] = bias_table[code[id]]; return; }
  id -= N2;
  const int N3 = 192 * 128;               // WxT[c][d]
  if (id < N3) { int c = id >> 7, d = id & 127; WxT[id] = f2bf(Wx[d * 192 + c]); return; }
  id -= N3;
  const int N4 = 8 * 64 * 128;            // c1wT[w][c][d]
  if (id < N4) {
    int w = id >> 13, c = (id >> 7) & 63, d = id & 127;
    c1wT[id] = f2bf(c1w[(w * 128 + d) * 64 + c]); return;
  }
  id -= N4;
  const int N5 = 8 * 64 * 64;             // c2wT[w][c][d]
  if (id < N5) {
    int w = id >> 12, c = (id >> 6) & 63, d = id & 63;
    c2wT[id] = f2bf(c2w[(w * 64 + d) * 64 + c]);
  }
}

// ---------------------------------------------------------------------------
// K1: x_proj = tok @ Wx + b_gru[0] -> bf16 TRANSPOSED [B,192,L]
// ---------------------------------------------------------------------------
__global__ __launch_bounds__(256) void k_xproj(
    const unsigned short* __restrict__ tokpad, const unsigned short* __restrict__ WxT,
    const float* __restrict__ bg, unsigned short* __restrict__ xprojT)
{
  __shared__ __align__(16) unsigned short At[128 * 136];
  __shared__ __align__(16) unsigned short Bt[192 * 136];
  int b = blockIdx.x >> 4;
  int l0 = (blockIdx.x & 15) << 7;
  int tid = threadIdx.x;
  for (int i = tid; i < 128 * 16; i += 256) {
    int row = i >> 4, c8 = i & 15;
    uint4 v = ((const uint4*)tokpad)[(b * LP + PAD + l0 + row) * 16 + c8];
    *((uint4*)&At[row * 136 + c8 * 8]) = v;
  }
  for (int i = tid; i < 192 * 16; i += 256) {
    int row = i >> 4, c8 = i & 15;
    uint4 v = ((const uint4*)WxT)[i];
    *((uint4*)&Bt[row * 136 + c8 * 8]) = v;
  }
  __syncthreads();
  int wave = tid >> 6, lane = tid & 63;
  int m = lane & 15, q = lane >> 4;
  f32x4 acc[2][12];
  #pragma unroll
  for (int mt = 0; mt < 2; ++mt)
    #pragma unroll
    for (int nt = 0; nt < 12; ++nt) acc[mt][nt] = (f32x4){0.f,0.f,0.f,0.f};
  #pragma unroll
  for (int ks = 0; ks < 4; ++ks) {
    int kof = ks * 32 + q * 8;
    short8 a[2], bb[12];
    #pragma unroll
    for (int mt = 0; mt < 2; ++mt)
      a[mt] = *(const short8*)&At[(wave * 32 + mt * 16 + m) * 136 + kof];
    #pragma unroll
    for (int nt = 0; nt < 12; ++nt)
      bb[nt] = *(const short8*)&Bt[(nt * 16 + m) * 136 + kof];
    #pragma unroll
    for (int mt = 0; mt < 2; ++mt)
      #pragma unroll
      for (int nt = 0; nt < 12; ++nt)
        acc[mt][nt] = __builtin_amdgcn_mfma_f32_16x16x32_bf16(a[mt], bb[nt], acc[mt][nt], 0, 0, 0);
  }
  #pragma unroll
  for (int mt = 0; mt < 2; ++mt) {
    int lrow = l0 + wave * 32 + mt * 16 + q * 4;
    #pragma unroll
    for (int nt = 0; nt < 12; ++nt) {
      int c = nt * 16 + m;                 // C col = lane&15
      float b0 = bg[c];
      us4 val;
      val.x = f2bf(acc[mt][nt][0] + b0);
      val.y = f2bf(acc[mt][nt][1] + b0);
      val.z = f2bf(acc[mt][nt][2] + b0);
      val.w = f2bf(acc[mt][nt][3] + b0);
      *((us4*)&xprojT[((size_t)b * 192 + c) * L_ + lrow]) = val;
    }
  }
}

// ---------------------------------------------------------------------------
// K2: conv1 = relu(conv8(tok,c1w)+c1b) -> bf16 l1pad rows [3,2051)
// ---------------------------------------------------------------------------
__global__ __launch_bounds__(256) void k_conv1(
    const unsigned short* __restrict__ tokpad, const unsigned short* __restrict__ c1wT,
    const float* __restrict__ c1b, unsigned short* __restrict__ l1pad)
{
  __shared__ __align__(16) unsigned short At[135 * 136];
  __shared__ __align__(16) unsigned short Bw[64 * 136];
  int b = blockIdx.x >> 4;
  int l0 = (blockIdx.x & 15) << 7;
  int tid = threadIdx.x;
  for (int i = tid; i < 135 * 16; i += 256) {
    int row = i >> 4, c8 = i & 15;
    uint4 v = ((const uint4*)tokpad)[(b * LP + l0 + row) * 16 + c8];
    *((uint4*)&At[row * 136 + c8 * 8]) = v;
  }
  int wave = tid >> 6, lane = tid & 63;
  int m = lane & 15, q = lane >> 4;
  f32x4 acc[2][4];
  #pragma unroll
  for (int mt = 0; mt < 2; ++mt)
    #pragma unroll
    for (int nt = 0; nt < 4; ++nt) acc[mt][nt] = (f32x4){0.f,0.f,0.f,0.f};
  for (int w = 0; w < 8; ++w) {
    __syncthreads();                       // covers At (w=0) and Bw reuse
    for (int i = tid; i < 64 * 16; i += 256) {
      int row = i >> 4, c8 = i & 15;
      uint4 v = ((const uint4*)c1wT)[(w * 64 + row) * 16 + c8];
      *((uint4*)&Bw[row * 136 + c8 * 8]) = v;
    }
    __syncthreads();
    #pragma unroll
    for (int ks = 0; ks < 4; ++ks) {
      int kof = ks * 32 + q * 8;
      short8 a[2], bb[4];
      #pragma unroll
      for (int mt = 0; mt < 2; ++mt)
        a[mt] = *(const short8*)&At[(wave * 32 + mt * 16 + m + w) * 136 + kof];
      #pragma unroll
      for (int nt = 0; nt < 4; ++nt)
        bb[nt] = *(const short8*)&Bw[(nt * 16 + m) * 136 + kof];
      #pragma unroll
      for (int mt = 0; mt < 2; ++mt)
        #pragma unroll
        for (int nt = 0; nt < 4; ++nt)
          acc[mt][nt] = __builtin_amdgcn_mfma_f32_16x16x32_bf16(a[mt], bb[nt], acc[mt][nt], 0, 0, 0);
    }
  }
  #pragma unroll
  for (int mt = 0; mt < 2; ++mt) {
    int lrow = l0 + wave * 32 + mt * 16 + q * 4;
    #pragma unroll
    for (int nt = 0; nt < 4; ++nt) {
      int c = nt * 16 + m;
      float bias = c1b[c];
      #pragma unroll
      for (int r = 0; r < 4; ++r) {
        float v = fmaxf(acc[mt][nt][r] + bias, 0.f);
        l1pad[(size_t)(b * LP + PAD + lrow + r) * 64 + c] = f2bf(v);
      }
    }
  }
}

// ---------------------------------------------------------------------------
// K3: conv2 (+c2b, pre h_t multiply) -> bf16 c2out [B,L,64]
// ---------------------------------------------------------------------------
__global__ __launch_bounds__(256) void k_conv2(
    const unsigned short* __restrict__ l1pad, const unsigned short* __restrict__ c2wT,
    const float* __restrict__ c2b, unsigned short* __restrict__ c2o)
{
  __shared__ __align__(16) unsigned short At[135 * 72];
  __shared__ __align__(16) unsigned short Bw[64 * 72];
  int b = blockIdx.x >> 4;
  int l0 = (blockIdx.x & 15) << 7;
  int tid = threadIdx.x;
  for (int i = tid; i < 135 * 8; i += 256) {
    int row = i >> 3, c8 = i & 7;
    uint4 v = ((const uint4*)l1pad)[(b * LP + l0 + row) * 8 + c8];
    *((uint4*)&At[row * 72 + c8 * 8]) = v;
  }
  int wave = tid >> 6, lane = tid & 63;
  int m = lane & 15, q = lane >> 4;
  f32x4 acc[2][4];
  #pragma unroll
  for (int mt = 0; mt < 2; ++mt)
    #pragma unroll
    for (int nt = 0; nt < 4; ++nt) acc[mt][nt] = (f32x4){0.f,0.f,0.f,0.f};
  for (int w = 0; w < 8; ++w) {
    __syncthreads();
    for (int i = tid; i < 64 * 8; i += 256) {
      int row = i >> 3, c8 = i & 7;
      uint4 v = ((const uint4*)c2wT)[(w * 64 + row) * 8 + c8];
      *((uint4*)&Bw[row * 72 + c8 * 8]) = v;
    }
    __syncthreads();
    #pragma unroll
    for (int ks = 0; ks < 2; ++ks) {
      int kof = ks * 32 + q * 8;
      short8 a[2], bb[4];
      #pragma unroll
      for (int mt = 0; mt < 2; ++mt)
        a[mt] = *(const short8*)&At[(wave * 32 + mt * 16 + m + w) * 72 + kof];
      #pragma unroll
      for (int nt = 0; nt < 4; ++nt)
        bb[nt] = *(const short8*)&Bw[(nt * 16 + m) * 72 + kof];
      #pragma unroll
      for (int mt = 0; mt < 2; ++mt)
        #pragma unroll
        for (int nt = 0; nt < 4; ++nt)
          acc[mt][nt] = __builtin_amdgcn_mfma_f32_16x16x32_bf16(a[mt], bb[nt], acc[mt][nt], 0, 0, 0);
    }
  }
  #pragma unroll
  for (int mt = 0; mt < 2; ++mt) {
    int lrow = l0 + wave * 32 + mt * 16 + q * 4;
    #pragma unroll
    for (int nt = 0; nt < 4; ++nt) {
      int c = nt * 16 + m;
      float bias = c2b[c];
      #pragma unroll
      for (int r = 0; r < 4; ++r)
        c2o[(size_t)(b * L_ + lrow + r) * 64 + c] = f2bf(acc[mt][nt][r] + bias);
    }
  }
}

// ---------------------------------------------------------------------------
// K4 v8: SINGLE-WAVE GRU scan, zero barriers. R6 post-mortem: with weights
// resident and vmem pipelined, the ~1175 cyc/step was the 3-wave structure
// itself (2 barriers + 3 exposed LDS latency round-trips per step). Now one
// wave per batch; lane j owns ALL 3 gates of column j (192 weights in VGPRs,
// 512-reg budget via waves_per_eu(1,1) — R5-verified). Gate math is fully
// lane-local. Only h[64] goes through LDS: ds_write own h, 16 broadcast
// ds_read_b128 — intra-wave lgkmcnt ordering, no s_barrier in the kernel.
// x loads: transposed [B,192,L], 8-step chunks prefetched one chunk ahead.
// ---------------------------------------------------------------------------
__global__ __launch_bounds__(64)
__attribute__((amdgpu_waves_per_eu(1, 1)))
void k_scan(
    const unsigned short* __restrict__ xprojT, const float* __restrict__ Wh,
    const float* __restrict__ bg, float* __restrict__ h_t)
{
  // 56 KB LDS backstop (hardware occupancy cap); h lives in first 64 floats.
  __shared__ __align__(16) float lds_pool[14336];
  float* h_lds = lds_pool;

  int b = blockIdx.x;
  int j = threadIdx.x;                    // 0..63, owns column j of all gates

#define DW(p, i, off) float4 p##i = {Wh[(4*i+0)*192+(off)], Wh[(4*i+1)*192+(off)], \
                                     Wh[(4*i+2)*192+(off)], Wh[(4*i+3)*192+(off)]};
#define DECL16(p, off) DW(p,0,off) DW(p,1,off) DW(p,2,off) DW(p,3,off) \
                       DW(p,4,off) DW(p,5,off) DW(p,6,off) DW(p,7,off) \
                       DW(p,8,off) DW(p,9,off) DW(p,10,off) DW(p,11,off) \
                       DW(p,12,off) DW(p,13,off) DW(p,14,off) DW(p,15,off)
  DECL16(wz, j)
  DECL16(wr, 64 + j)
  DECL16(wh, 128 + j)
#undef DECL16
#undef DW
  // Opacity pin: asm outputs cannot be rematerialized from memory.
#define OP4(p, i) asm volatile("" : "+v"(p##i.x), "+v"(p##i.y), "+v"(p##i.z), "+v"(p##i.w));
#define OP16(p) OP4(p,0) OP4(p,1) OP4(p,2) OP4(p,3) OP4(p,4) OP4(p,5) OP4(p,6) OP4(p,7) \
                OP4(p,8) OP4(p,9) OP4(p,10) OP4(p,11) OP4(p,12) OP4(p,13) OP4(p,14) OP4(p,15)
  OP16(wz) OP16(wr) OP16(wh)
#undef OP16
#undef OP4

  float bz = bg[192 + j], br = bg[256 + j], bh = bg[320 + j];

  h_lds[j] = 0.f;
  float hcur = 0.f;
  const float4* hl4 = (const float4*)h_lds;

  const unsigned short* xz_p = xprojT + ((size_t)b * 192 + j) * L_;
  const unsigned short* xr_p = xprojT + ((size_t)b * 192 + 64 + j) * L_;
  const unsigned short* xh_p = xprojT + ((size_t)b * 192 + 128 + j) * L_;

  uint4 cz = ((const uint4*)xz_p)[0];
  uint4 cr = ((const uint4*)xr_p)[0];
  uint4 ch = ((const uint4*)xh_p)[0];

#define ACC1(i) { float4 h4 = hl4[i]; \
    az0 = fmaf(h4.x, wz##i.x, az0); az1 = fmaf(h4.y, wz##i.y, az1); \
    az2 = fmaf(h4.z, wz##i.z, az2); az3 = fmaf(h4.w, wz##i.w, az3); \
    ar0 = fmaf(h4.x, wr##i.x, ar0); ar1 = fmaf(h4.y, wr##i.y, ar1); \
    ar2 = fmaf(h4.z, wr##i.z, ar2); ar3 = fmaf(h4.w, wr##i.w, ar3); \
    ah0 = fmaf(h4.x, wh##i.x, ah0); ah1 = fmaf(h4.y, wh##i.y, ah1); \
    ah2 = fmaf(h4.z, wh##i.z, ah2); ah3 = fmaf(h4.w, wh##i.w, ah3); }

#define STEP(XZ, XR, XH) { \
    float az0 = bz, az1 = 0.f, az2 = 0.f, az3 = 0.f; \
    float ar0 = br, ar1 = 0.f, ar2 = 0.f, ar3 = 0.f; \
    float ah0 = bh, ah1 = 0.f, ah2 = 0.f, ah3 = 0.f; \
    ACC1(0)  ACC1(1)  ACC1(2)  ACC1(3) \
    ACC1(4)  ACC1(5)  ACC1(6)  ACC1(7) \
    ACC1(8)  ACC1(9)  ACC1(10) ACC1(11) \
    ACC1(12) ACC1(13) ACC1(14) ACC1(15) \
    float az = (az0 + az1) + (az2 + az3); \
    float ar = (ar0 + ar1) + (ar2 + ar3); \
    float ah = (ah0 + ah1) + (ah2 + ah3); \
    float xz = bf2f((unsigned short)(XZ)); \
    float xr = bf2f((unsigned short)(XR)); \
    float xh = bf2f((unsigned short)(XH)); \
    float z = 1.f / (1.f + __expf(-(xz + az))); \
    float r = 1.f / (1.f + __expf(-(xr + ar))); \
    float e2 = __expf(-2.f * (xh + r * ah)); \
    float hhv = fmaf(2.f, __frcp_rn(1.f + e2), -1.f); \
    hcur = z * hcur + (1.f - z) * hhv; \
    h_lds[j] = hcur; }

  for (int c = 0; c < 256; ++c) {         // 256 chunks x 8 steps
    int cn = (c + 1 < 256) ? c + 1 : c;
    uint4 nz = ((const uint4*)xz_p)[cn];
    uint4 nr = ((const uint4*)xr_p)[cn];
    uint4 nh = ((const uint4*)xh_p)[cn];
    STEP(cz.x & 0xffffu, cr.x & 0xffffu, ch.x & 0xffffu)
    STEP(cz.x >> 16,     cr.x >> 16,     ch.x >> 16)
    STEP(cz.y & 0xffffu, cr.y & 0xffffu, ch.y & 0xffffu)
    STEP(cz.y >> 16,     cr.y >> 16,     ch.y >> 16)
    STEP(cz.z & 0xffffu, cr.z & 0xffffu, ch.z & 0xffffu)
    STEP(cz.z >> 16,     cr.z >> 16,     ch.z >> 16)
    STEP(cz.w & 0xffffu, cr.w & 0xffffu, ch.w & 0xffffu)
    STEP(cz.w >> 16,     cr.w >> 16,     ch.w >> 16)
    cz = nz; cr = nr; ch = nh;
  }
#undef STEP
#undef ACC1
  h_t[b * 64 + j] = hcur;
}

// ---------------------------------------------------------------------------
// K5: per-batch tail: L2=c2o*h_t -> l2norm -> conv3 -> softmax alpha ->
//     n_hat = sum alpha*tok -> logits = tok.n_hat + bias -> softmax -> out
// ---------------------------------------------------------------------------
__global__ __launch_bounds__(256) void k_final(
    const unsigned short* __restrict__ tokpad, const unsigned short* __restrict__ c2o,
    const float* __restrict__ h_t, const float* __restrict__ c3w,
    const float* __restrict__ c3b, const float* __restrict__ biasg,
    float* __restrict__ out)
{
  __shared__ float Lf[71 * 65];
  __shared__ float a_lds[2048];
  __shared__ float l_lds[2048];
  __shared__ float red[256];
  __shared__ float nred[512];
  __shared__ float nhat[128];
  __shared__ float ht[64];
  __shared__ float c3[512];
  int b = blockIdx.x, tid = threadIdx.x, lane = tid & 63, wave = tid >> 6;
  if (tid < 64) ht[tid] = h_t[b * 64 + tid];
  for (int i = tid; i < 512; i += 256) c3[i] = c3w[i];
  float c3bias = c3b[0];
  __syncthreads();
  // ---- pass 1: a_logits via normalized features + conv3 (tiles of 64 l) ----
  for (int tile = 0; tile < 32; ++tile) {
    int lt = tile << 6;
    for (int i0 = wave; i0 < 71; i0 += 4) {
      int l = lt - 3 + i0;
      float v = 0.f;
      if (l >= 0 && l < L_) v = bf2f(c2o[((size_t)b * L_ + l) * 64 + lane]) * ht[lane];
      float ss = v * v;
      #pragma unroll
      for (int msk = 1; msk < 64; msk <<= 1) ss += __shfl_xor(ss, msk);
      Lf[i0 * 65 + lane] = v * rsqrtf(ss + 1e-12f);
    }
    __syncthreads();
    {
      int u = lane, part = wave;
      float p = 0.f;
      #pragma unroll
      for (int w = 0; w < 8; ++w)
        #pragma unroll
        for (int cc = 0; cc < 16; ++cc) {
          int c = part * 16 + cc;
          p += Lf[(u + w) * 65 + c] * c3[w * 64 + c];
        }
      red[tid] = p;
    }
    __syncthreads();
    if (tid < 64) a_lds[lt + tid] = red[tid] + red[64 + tid] + red[128 + tid] + red[192 + tid] + c3bias;
    __syncthreads();
  }
  // ---- pass 2: softmax alpha over 2048 ----
  {
    float mx = -1e30f;
    for (int i = tid; i < 2048; i += 256) mx = fmaxf(mx, a_lds[i]);
    #pragma unroll
    for (int msk = 1; msk < 64; msk <<= 1) mx = fmaxf(mx, __shfl_xor(mx, msk));
    if (lane == 0) red[wave] = mx;
    __syncthreads();
    mx = fmaxf(fmaxf(red[0], red[1]), fmaxf(red[2], red[3]));
    float sm = 0.f;
    for (int i = tid; i < 2048; i += 256) sm += __expf(a_lds[i] - mx);
    #pragma unroll
    for (int msk = 1; msk < 64; msk <<= 1) sm += __shfl_xor(sm, msk);
    __syncthreads();
    if (lane == 0) red[wave] = sm;
    __syncthreads();
    sm = red[0] + red[1] + red[2] + red[3];
    float inv = 1.f / sm;
    for (int i = tid; i < 2048; i += 256) a_lds[i] = __expf(a_lds[i] - mx) * inv;
    __syncthreads();
  }
  // ---- pass 3: n_hat[128] = sum_l alpha_l * tok[l][:] ----
  {
    int d2 = tid & 63, g = tid >> 6;
    float ax = 0.f, ay = 0.f;
    for (int l = g; l < L_; l += 4) {
      unsigned int uu = *(const unsigned int*)&tokpad[((size_t)b * LP + PAD + l) * 128 + d2 * 2];
      float al = a_lds[l];
      ax += al * bf2f((unsigned short)(uu & 0xffffu));
      ay += al * bf2f((unsigned short)(uu >> 16));
    }
    nred[g * 128 + d2 * 2] = ax;
    nred[g * 128 + d2 * 2 + 1] = ay;
    __syncthreads();
    if (tid < 128) nhat[tid] = nred[tid] + nred[128 + tid] + nred[256 + tid] + nred[384 + tid];
    __syncthreads();
  }
  // ---- pass 4: logits = tok . n_hat + bias ----
  for (int li = 0; li < 8; ++li) {
    int l = li * 256 + tid;
    const uint4* rowp = (const uint4*)&tokpad[((size_t)b * LP + PAD + l) * 128];
    float s = 0.f;
    #pragma unroll
    for (int jj = 0; jj < 16; ++jj) {
      uint4 uu = rowp[jj];
      s += bf2f((unsigned short)(uu.x & 0xffffu)) * nhat[jj*8+0]
         + bf2f((unsigned short)(uu.x >> 16))     * nhat[jj*8+1]
         + bf2f((unsigned short)(uu.y & 0xffffu)) * nhat[jj*8+2]
         + bf2f((unsigned short)(uu.y >> 16))     * nhat[jj*8+3]
         + bf2f((unsigned short)(uu.z & 0xffffu)) * nhat[jj*8+4]
         + bf2f((unsigned short)(uu.z >> 16))     * nhat[jj*8+5]
         + bf2f((unsigned short)(uu.w & 0xffffu)) * nhat[jj*8+6]
         + bf2f((unsigned short)(uu.w >> 16))     * nhat[jj*8+7];
    }
    l_lds[l] = s + biasg[b * L_ + l];
  }
  __syncthreads();
  // ---- pass 5: final softmax -> out ----
  {
    float mx = -1e30f;
    for (int i = tid; i < 2048; i += 256) mx = fmaxf(mx, l_lds[i]);
    #pragma unroll
    for (int msk = 1; msk < 64; msk <<= 1) mx = fmaxf(mx, __shfl_xor(mx, msk));
    __syncthreads();
    if (lane == 0) red[wave] = mx;
    __syncthreads();
    mx = fmaxf(fmaxf(red[0], red[1]), fmaxf(red[2], red[3]));
    float sm = 0.f;
    for (int i = tid; i < 2048; i += 256) sm += __expf(l_lds[i] - mx);
    #pragma unroll
    for (int msk = 1; msk < 64; msk <<= 1) sm += __shfl_xor(sm, msk);
    __syncthreads();
    if (lane == 0) red[wave] = sm;
    __syncthreads();
    sm = red[0] + red[1] + red[2] + red[3];
    float inv = 1.f / sm;
    for (int i = tid; i < 2048; i += 256) out[b * L_ + i] = __expf(l_lds[i] - mx) * inv;
  }
}

// ---------------------------------------------------------------------------
extern "C" void kernel_launch(void* const* d_in, const int* in_sizes, int n_in,
                              void* d_out, int out_size, void* d_ws, size_t ws_size,
                              hipStream_t stream) {
  const int*   code = (const int*)d_in[0];
  const float* E    = (const float*)d_in[1];
  const float* bt   = (const float*)d_in[2];
  const float* Wx   = (const float*)d_in[3];
  const float* Wh   = (const float*)d_in[4];
  const float* bg   = (const float*)d_in[5];
  const float* c1w  = (const float*)d_in[6];
  const float* c1b  = (const float*)d_in[7];
  const float* c2w  = (const float*)d_in[8];
  const float* c2b  = (const float*)d_in[9];
  const float* c3w  = (const float*)d_in[10];
  const float* c3b  = (const float*)d_in[11];
  char* ws = (char*)d_ws;
  unsigned short* tokpad = (unsigned short*)(ws);               // 33,685,504 B
  unsigned short* l1pad  = (unsigned short*)(ws + 33685504);    // 16,842,752 B
  unsigned short* xprojT = (unsigned short*)(ws + 50528256);    // 50,331,648 B
  unsigned short* c2o    = (unsigned short*)(ws + 100859904);   // 16,777,216 B
  unsigned short* WxT    = (unsigned short*)(ws + 117637120);   //     49,152 B
  unsigned short* c1wT   = (unsigned short*)(ws + 117686272);   //    131,072 B
  unsigned short* c2wT   = (unsigned short*)(ws + 117817344);   //     65,536 B
  float*          htp    = (float*)(ws + 117882880);            //     16,384 B
  float*          biasg  = (float*)(ws + 117899264);            //    524,288 B
  // total ws use: 118,423,552 B

  k_prep <<<9232, 256, 0, stream>>>(code, E, bt, Wx, c1w, c2w, tokpad, l1pad, WxT, c1wT, c2wT, biasg);
  k_xproj<<<1024, 256, 0, stream>>>(tokpad, WxT, bg, xprojT);
  k_scan <<<64, 64, 0, stream>>>(xprojT, Wh, bg, htp);
  k_conv1<<<1024, 256, 0, stream>>>(tokpad, c1wT, c1b, l1pad);
  k_conv2<<<1024, 256, 0, stream>>>(l1pad, c2wT, c2b, c2o);
  k_final<<<64, 256, 0, stream>>>(tokpad, c2o, htp, c3w, c3b, biasg, (float*)d_out);
}

// Round 9
// 2131.279 us; speedup vs baseline: 1.0042x; 1.0042x over previous
//
#include <hip/hip_runtime.h>

#define B_ 64
#define L_ 2048
#define D_ 128
#define LP 2056   // padded rows per batch (3 left, 5 right incl. alignment)
#define PAD 3     // SAME-pad left for W=8

typedef __attribute__((ext_vector_type(8))) short short8;
typedef __attribute__((ext_vector_type(4))) float f32x4;
typedef __attribute__((ext_vector_type(4))) unsigned short us4;

static __device__ __forceinline__ float bf2f(unsigned short u) {
  return __uint_as_float(((unsigned int)u) << 16);
}
static __device__ __forceinline__ unsigned short f2bf(float f) {
  unsigned int x = __float_as_uint(f);
  unsigned int r = (x + 0x7fffu + ((x >> 16) & 1u)) >> 16;  // RNE
  return (unsigned short)r;
}

// ---------------------------------------------------------------------------
// K0: gather tok -> bf16 padded [B,LP,128]; zero l1pad's pad rows; gather bias;
//     transpose weights to bf16 [n][k] layouts. WhT[192][64] for MFMA scan.
// ---------------------------------------------------------------------------
__global__ __launch_bounds__(256) void k_prep(
    const int* __restrict__ code, const float* __restrict__ E,
    const float* __restrict__ bias_table, const float* __restrict__ Wx,
    const float* __restrict__ c1w, const float* __restrict__ c2w,
    const float* __restrict__ Wh,
    unsigned short* __restrict__ tokpad, unsigned short* __restrict__ l1pad,
    unsigned short* __restrict__ WxT, unsigned short* __restrict__ c1wT,
    unsigned short* __restrict__ c2wT, float* __restrict__ biasg,
    unsigned short* __restrict__ WhT)
{
  int id = blockIdx.x * 256 + threadIdx.x;
  const int N0 = B_ * LP * 16;            // tokpad in uint4 (8 bf16) chunks
  if (id < N0) {
    int b = id / (LP * 16); int rem = id % (LP * 16);
    int row = rem >> 4, c8 = rem & 15;
    uint4 o = {0u,0u,0u,0u};
    if (row >= PAD && row < PAD + L_) {
      int cd = code[b * L_ + (row - PAD)];
      const float4* e = (const float4*)(E + (size_t)cd * D_ + c8 * 8);
      float4 e0 = e[0], e1 = e[1];
      o.x = f2bf(e0.x) | ((unsigned int)f2bf(e0.y) << 16);
      o.y = f2bf(e0.z) | ((unsigned int)f2bf(e0.w) << 16);
      o.z = f2bf(e1.x) | ((unsigned int)f2bf(e1.y) << 16);
      o.w = f2bf(e1.z) | ((unsigned int)f2bf(e1.w) << 16);
    }
    ((uint4*)tokpad)[id] = o;
    return;
  }
  id -= N0;
  const int N1 = B_ * 8 * 8;              // l1pad pad rows (8 rows x 8 chunks)
  if (id < N1) {
    int b = id >> 6; int rem = id & 63; int ri = rem >> 3, c8 = rem & 7;
    int row = ri < 3 ? ri : (L_ + ri);    // 0,1,2, 2051..2055
    uint4 z = {0u,0u,0u,0u};
    ((uint4*)l1pad)[(b * LP + row) * 8 + c8] = z;
    return;
  }
  id -= N1;
  const int N2 = B_ * L_;
  if (id < N2) { biasg[id] = bias_table[code[id]]; return; }
  id -= N2;
  const int N3 = 192 * 128;               // WxT[c][d]
  if (id < N3) { int c = id >> 7, d = id & 127; WxT[id] = f2bf(Wx[d * 192 + c]); return; }
  id -= N3;
  const int N4 = 8 * 64 * 128;            // c1wT[w][c][d]
  if (id < N4) {
    int w = id >> 13, c = (id >> 7) & 63, d = id & 127;
    c1wT[id] = f2bf(c1w[(w * 128 + d) * 64 + c]); return;
  }
  id -= N4;
  const int N5 = 8 * 64 * 64;             // c2wT[w][c][d]
  if (id < N5) {
    int w = id >> 12, c = (id >> 6) & 63, d = id & 63;
    c2wT[id] = f2bf(c2w[(w * 64 + d) * 64 + c]); return;
  }
  id -= N5;
  const int N6 = 192 * 64;                // WhT[n][k] = Wh[k][n]
  if (id < N6) {
    int nn = id >> 6, k = id & 63;
    WhT[id] = f2bf(Wh[k * 192 + nn]);
  }
}

// ---------------------------------------------------------------------------
// K1: x_proj = tok @ Wx + b_gru[0] -> bf16 TRANSPOSED [B,192,L]
// ---------------------------------------------------------------------------
__global__ __launch_bounds__(256) void k_xproj(
    const unsigned short* __restrict__ tokpad, const unsigned short* __restrict__ WxT,
    const float* __restrict__ bg, unsigned short* __restrict__ xprojT)
{
  __shared__ __align__(16) unsigned short At[128 * 136];
  __shared__ __align__(16) unsigned short Bt[192 * 136];
  int b = blockIdx.x >> 4;
  int l0 = (blockIdx.x & 15) << 7;
  int tid = threadIdx.x;
  for (int i = tid; i < 128 * 16; i += 256) {
    int row = i >> 4, c8 = i & 15;
    uint4 v = ((const uint4*)tokpad)[(b * LP + PAD + l0 + row) * 16 + c8];
    *((uint4*)&At[row * 136 + c8 * 8]) = v;
  }
  for (int i = tid; i < 192 * 16; i += 256) {
    int row = i >> 4, c8 = i & 15;
    uint4 v = ((const uint4*)WxT)[i];
    *((uint4*)&Bt[row * 136 + c8 * 8]) = v;
  }
  __syncthreads();
  int wave = tid >> 6, lane = tid & 63;
  int m = lane & 15, q = lane >> 4;
  f32x4 acc[2][12];
  #pragma unroll
  for (int mt = 0; mt < 2; ++mt)
    #pragma unroll
    for (int nt = 0; nt < 12; ++nt) acc[mt][nt] = (f32x4){0.f,0.f,0.f,0.f};
  #pragma unroll
  for (int ks = 0; ks < 4; ++ks) {
    int kof = ks * 32 + q * 8;
    short8 a[2], bb[12];
    #pragma unroll
    for (int mt = 0; mt < 2; ++mt)
      a[mt] = *(const short8*)&At[(wave * 32 + mt * 16 + m) * 136 + kof];
    #pragma unroll
    for (int nt = 0; nt < 12; ++nt)
      bb[nt] = *(const short8*)&Bt[(nt * 16 + m) * 136 + kof];
    #pragma unroll
    for (int mt = 0; mt < 2; ++mt)
      #pragma unroll
      for (int nt = 0; nt < 12; ++nt)
        acc[mt][nt] = __builtin_amdgcn_mfma_f32_16x16x32_bf16(a[mt], bb[nt], acc[mt][nt], 0, 0, 0);
  }
  #pragma unroll
  for (int mt = 0; mt < 2; ++mt) {
    int lrow = l0 + wave * 32 + mt * 16 + q * 4;
    #pragma unroll
    for (int nt = 0; nt < 12; ++nt) {
      int c = nt * 16 + m;                 // C col = lane&15
      float b0 = bg[c];
      us4 val;
      val.x = f2bf(acc[mt][nt][0] + b0);
      val.y = f2bf(acc[mt][nt][1] + b0);
      val.z = f2bf(acc[mt][nt][2] + b0);
      val.w = f2bf(acc[mt][nt][3] + b0);
      *((us4*)&xprojT[((size_t)b * 192 + c) * L_ + lrow]) = val;
    }
  }
}

// ---------------------------------------------------------------------------
// K2: conv1 = relu(conv8(tok,c1w)+c1b) -> bf16 l1pad rows [3,2051)
// ---------------------------------------------------------------------------
__global__ __launch_bounds__(256) void k_conv1(
    const unsigned short* __restrict__ tokpad, const unsigned short* __restrict__ c1wT,
    const float* __restrict__ c1b, unsigned short* __restrict__ l1pad)
{
  __shared__ __align__(16) unsigned short At[135 * 136];
  __shared__ __align__(16) unsigned short Bw[64 * 136];
  int b = blockIdx.x >> 4;
  int l0 = (blockIdx.x & 15) << 7;
  int tid = threadIdx.x;
  for (int i = tid; i < 135 * 16; i += 256) {
    int row = i >> 4, c8 = i & 15;
    uint4 v = ((const uint4*)tokpad)[(b * LP + l0 + row) * 16 + c8];
    *((uint4*)&At[row * 136 + c8 * 8]) = v;
  }
  int wave = tid >> 6, lane = tid & 63;
  int m = lane & 15, q = lane >> 4;
  f32x4 acc[2][4];
  #pragma unroll
  for (int mt = 0; mt < 2; ++mt)
    #pragma unroll
    for (int nt = 0; nt < 4; ++nt) acc[mt][nt] = (f32x4){0.f,0.f,0.f,0.f};
  for (int w = 0; w < 8; ++w) {
    __syncthreads();                       // covers At (w=0) and Bw reuse
    for (int i = tid; i < 64 * 16; i += 256) {
      int row = i >> 4, c8 = i & 15;
      uint4 v = ((const uint4*)c1wT)[(w * 64 + row) * 16 + c8];
      *((uint4*)&Bw[row * 136 + c8 * 8]) = v;
    }
    __syncthreads();
    #pragma unroll
    for (int ks = 0; ks < 4; ++ks) {
      int kof = ks * 32 + q * 8;
      short8 a[2], bb[4];
      #pragma unroll
      for (int mt = 0; mt < 2; ++mt)
        a[mt] = *(const short8*)&At[(wave * 32 + mt * 16 + m + w) * 136 + kof];
      #pragma unroll
      for (int nt = 0; nt < 4; ++nt)
        bb[nt] = *(const short8*)&Bw[(nt * 16 + m) * 136 + kof];
      #pragma unroll
      for (int mt = 0; mt < 2; ++mt)
        #pragma unroll
        for (int nt = 0; nt < 4; ++nt)
          acc[mt][nt] = __builtin_amdgcn_mfma_f32_16x16x32_bf16(a[mt], bb[nt], acc[mt][nt], 0, 0, 0);
    }
  }
  #pragma unroll
  for (int mt = 0; mt < 2; ++mt) {
    int lrow = l0 + wave * 32 + mt * 16 + q * 4;
    #pragma unroll
    for (int nt = 0; nt < 4; ++nt) {
      int c = nt * 16 + m;
      float bias = c1b[c];
      #pragma unroll
      for (int r = 0; r < 4; ++r) {
        float v = fmaxf(acc[mt][nt][r] + bias, 0.f);
        l1pad[(size_t)(b * LP + PAD + lrow + r) * 64 + c] = f2bf(v);
      }
    }
  }
}

// ---------------------------------------------------------------------------
// K3: conv2 (+c2b, pre h_t multiply) -> bf16 c2out [B,L,64]
// ---------------------------------------------------------------------------
__global__ __launch_bounds__(256) void k_conv2(
    const unsigned short* __restrict__ l1pad, const unsigned short* __restrict__ c2wT,
    const float* __restrict__ c2b, unsigned short* __restrict__ c2o)
{
  __shared__ __align__(16) unsigned short At[135 * 72];
  __shared__ __align__(16) unsigned short Bw[64 * 72];
  int b = blockIdx.x >> 4;
  int l0 = (blockIdx.x & 15) << 7;
  int tid = threadIdx.x;
  for (int i = tid; i < 135 * 8; i += 256) {
    int row = i >> 3, c8 = i & 7;
    uint4 v = ((const uint4*)l1pad)[(b * LP + l0 + row) * 8 + c8];
    *((uint4*)&At[row * 72 + c8 * 8]) = v;
  }
  int wave = tid >> 6, lane = tid & 63;
  int m = lane & 15, q = lane >> 4;
  f32x4 acc[2][4];
  #pragma unroll
  for (int mt = 0; mt < 2; ++mt)
    #pragma unroll
    for (int nt = 0; nt < 4; ++nt) acc[mt][nt] = (f32x4){0.f,0.f,0.f,0.f};
  for (int w = 0; w < 8; ++w) {
    __syncthreads();
    for (int i = tid; i < 64 * 8; i += 256) {
      int row = i >> 3, c8 = i & 7;
      uint4 v = ((const uint4*)c2wT)[(w * 64 + row) * 8 + c8];
      *((uint4*)&Bw[row * 72 + c8 * 8]) = v;
    }
    __syncthreads();
    #pragma unroll
    for (int ks = 0; ks < 2; ++ks) {
      int kof = ks * 32 + q * 8;
      short8 a[2], bb[4];
      #pragma unroll
      for (int mt = 0; mt < 2; ++mt)
        a[mt] = *(const short8*)&At[(wave * 32 + mt * 16 + m + w) * 72 + kof];
      #pragma unroll
      for (int nt = 0; nt < 4; ++nt)
        bb[nt] = *(const short8*)&Bw[(nt * 16 + m) * 72 + kof];
      #pragma unroll
      for (int mt = 0; mt < 2; ++mt)
        #pragma unroll
        for (int nt = 0; nt < 4; ++nt)
          acc[mt][nt] = __builtin_amdgcn_mfma_f32_16x16x32_bf16(a[mt], bb[nt], acc[mt][nt], 0, 0, 0);
    }
  }
  #pragma unroll
  for (int mt = 0; mt < 2; ++mt) {
    int lrow = l0 + wave * 32 + mt * 16 + q * 4;
    #pragma unroll
    for (int nt = 0; nt < 4; ++nt) {
      int c = nt * 16 + m;
      float bias = c2b[c];
      #pragma unroll
      for (int r = 0; r < 4; ++r)
        c2o[(size_t)(b * L_ + lrow + r) * 64 + c] = f2bf(acc[mt][nt][r] + bias);
    }
  }
}

// ---------------------------------------------------------------------------
// K4 v9: MFMA GRU scan, transposed: D[out16][batch16] = WhT_tile . h^T.
//  - A-operand = Wh (loop-invariant) -> 6 frags pinned in VGPRs.
//  - Wave w owns out-tiles {w,4+w,8+w} = z/r/hh for h-cols 16w..16w+15:
//    gate math lane-local (lane = (batch=lane&15, quad)).
//  - D row=(q*4+reg)=out-col, D col=batch: new-h = 4 consecutive bf16
//    -> one ds_write_b64 (2-way bank = free; fixes R3's 1M conflicts).
//  - h double-buffered, ONE raw lgkmcnt barrier per step (x loads never
//    drained). 2 ds_read_b128 per step. 4 WGs x 16 batches.
// ---------------------------------------------------------------------------
#define BARRIER() asm volatile("s_waitcnt lgkmcnt(0)\n\ts_barrier" ::: "memory")

__global__ __launch_bounds__(256)
__attribute__((amdgpu_waves_per_eu(1, 1)))
void k_scan(
    const unsigned short* __restrict__ xprojT, const unsigned short* __restrict__ WhT,
    const float* __restrict__ bg, float* __restrict__ h_t)
{
  // 57344 B LDS (occupancy backstop). hbuf0 at 0, hbuf1 at 1152 shorts.
  __shared__ __align__(16) unsigned short pool[28672];
  unsigned short* hbuf0 = pool;           // [16][72] bf16
  unsigned short* hbuf1 = pool + 1152;

  int tid = threadIdx.x;
  int w = tid >> 6, lane = tid & 63;
  int n = lane & 15, q = lane >> 4;       // n = batch-in-group / A-row m; q = quad
  int b0 = blockIdx.x * 16;

  // A-frags: A[m=lane&15][k=c*32+q*8+j] = WhT[tile*16+m][k]; row = 8 uint4s.
  const uint4* whp = (const uint4*)WhT;
  uint4 aZ0u = whp[(w * 16 + n) * 8 + q];
  uint4 aZ1u = whp[(w * 16 + n) * 8 + 4 + q];
  uint4 aR0u = whp[(64 + w * 16 + n) * 8 + q];
  uint4 aR1u = whp[(64 + w * 16 + n) * 8 + 4 + q];
  uint4 aH0u = whp[(128 + w * 16 + n) * 8 + q];
  uint4 aH1u = whp[(128 + w * 16 + n) * 8 + 4 + q];
#define OPQ(v) asm volatile("" : "+v"(v.x), "+v"(v.y), "+v"(v.z), "+v"(v.w));
  OPQ(aZ0u) OPQ(aZ1u) OPQ(aR0u) OPQ(aR1u) OPQ(aH0u) OPQ(aH1u)
#undef OPQ
  short8 aZ0 = __builtin_bit_cast(short8, aZ0u);
  short8 aZ1 = __builtin_bit_cast(short8, aZ1u);
  short8 aR0 = __builtin_bit_cast(short8, aR0u);
  short8 aR1 = __builtin_bit_cast(short8, aR1u);
  short8 aH0 = __builtin_bit_cast(short8, aH0u);
  short8 aH1 = __builtin_bit_cast(short8, aH1u);

  int colb = w * 16 + q * 4;              // this lane's 4 gate columns
  f32x4 bz4 = *(const f32x4*)&bg[192 + colb];
  f32x4 br4 = *(const f32x4*)&bg[256 + colb];
  f32x4 bh4 = *(const f32x4*)&bg[320 + colb];

  // 12 x streams: batch b0+n, col g*64 + colb + r, contiguous in t.
  const unsigned short* xb = xprojT + ((size_t)(b0 + n) * 192 + colb) * L_;
#define XS(g, r) ((const uint4*)(xb + (size_t)((g) * 64 + (r)) * L_))
  uint4 cz0 = XS(0,0)[0], cz1 = XS(0,1)[0], cz2 = XS(0,2)[0], cz3 = XS(0,3)[0];
  uint4 cr0 = XS(1,0)[0], cr1 = XS(1,1)[0], cr2 = XS(1,2)[0], cr3 = XS(1,3)[0];
  uint4 ch0 = XS(2,0)[0], ch1 = XS(2,1)[0], ch2 = XS(2,2)[0], ch3 = XS(2,3)[0];

  // zero h buffer 0 (each lane zeroes its own write slot) + h_old regs
  *((uint2*)&hbuf0[n * 72 + colb]) = (uint2){0u, 0u};
  f32x4 h4 = (f32x4){0.f, 0.f, 0.f, 0.f};

  int wrow = n * 72;                      // LDS row base (shorts) for batch n

#define GATE(r, XZ, XR, XH) { \
    float zg = 1.f / (1.f + __expf(-(Dz[r] + bz4[r] + bf2f((unsigned short)(XZ))))); \
    float rg = 1.f / (1.f + __expf(-(Dr[r] + br4[r] + bf2f((unsigned short)(XR))))); \
    float hp = bf2f((unsigned short)(XH)) + rg * (Dh[r] + bh4[r]); \
    float e2 = __expf(-2.f * hp); \
    float hh = fmaf(2.f, __frcp_rn(1.f + e2), -1.f); \
    h4[r] = zg * h4[r] + (1.f - zg) * hh; }

#define STEP(RB, WB, CMP, SH) { \
    BARRIER(); \
    short8 hb0 = *(const short8*)&RB[wrow + q * 8]; \
    short8 hb1 = *(const short8*)&RB[wrow + 32 + q * 8]; \
    f32x4 Dz = (f32x4){0.f,0.f,0.f,0.f}; \
    f32x4 Dr = (f32x4){0.f,0.f,0.f,0.f}; \
    f32x4 Dh = (f32x4){0.f,0.f,0.f,0.f}; \
    Dz = __builtin_amdgcn_mfma_f32_16x16x32_bf16(aZ0, hb0, Dz, 0, 0, 0); \
    Dr = __builtin_amdgcn_mfma_f32_16x16x32_bf16(aR0, hb0, Dr, 0, 0, 0); \
    Dh = __builtin_amdgcn_mfma_f32_16x16x32_bf16(aH0, hb0, Dh, 0, 0, 0); \
    Dz = __builtin_amdgcn_mfma_f32_16x16x32_bf16(aZ1, hb1, Dz, 0, 0, 0); \
    Dr = __builtin_amdgcn_mfma_f32_16x16x32_bf16(aR1, hb1, Dr, 0, 0, 0); \
    Dh = __builtin_amdgcn_mfma_f32_16x16x32_bf16(aH1, hb1, Dh, 0, 0, 0); \
    GATE(0, cz0.CMP >> SH, cr0.CMP >> SH, ch0.CMP >> SH) \
    GATE(1, cz1.CMP >> SH, cr1.CMP >> SH, ch1.CMP >> SH) \
    GATE(2, cz2.CMP >> SH, cr2.CMP >> SH, ch2.CMP >> SH) \
    GATE(3, cz3.CMP >> SH, cr3.CMP >> SH, ch3.CMP >> SH) \
    uint2 hv; \
    hv.x = (unsigned int)f2bf(h4[0]) | ((unsigned int)f2bf(h4[1]) << 16); \
    hv.y = (unsigned int)f2bf(h4[2]) | ((unsigned int)f2bf(h4[3]) << 16); \
    *((uint2*)&WB[wrow + colb]) = hv; }

  for (int c8 = 0; c8 < 256; ++c8) {
    int cn = (c8 + 1 < 256) ? c8 + 1 : c8;
    uint4 nz0 = XS(0,0)[cn], nz1 = XS(0,1)[cn], nz2 = XS(0,2)[cn], nz3 = XS(0,3)[cn];
    uint4 nr0 = XS(1,0)[cn], nr1 = XS(1,1)[cn], nr2 = XS(1,2)[cn], nr3 = XS(1,3)[cn];
    uint4 nh0 = XS(2,0)[cn], nh1 = XS(2,1)[cn], nh2 = XS(2,2)[cn], nh3 = XS(2,3)[cn];
    STEP(hbuf0, hbuf1, x, 0)  STEP(hbuf1, hbuf0, x, 16)
    STEP(hbuf0, hbuf1, y, 0)  STEP(hbuf1, hbuf0, y, 16)
    STEP(hbuf0, hbuf1, z, 0)  STEP(hbuf1, hbuf0, z, 16)
    STEP(hbuf0, hbuf1, w, 0)  STEP(hbuf1, hbuf0, w, 16)
    cz0 = nz0; cz1 = nz1; cz2 = nz2; cz3 = nz3;
    cr0 = nr0; cr1 = nr1; cr2 = nr2; cr3 = nr3;
    ch0 = nh0; ch1 = nh1; ch2 = nh2; ch3 = nh3;
  }
#undef STEP
#undef GATE
#undef XS
  *((f32x4*)&h_t[(b0 + n) * 64 + colb]) = h4;
}

// ---------------------------------------------------------------------------
// K5: per-batch tail: L2=c2o*h_t -> l2norm -> conv3 -> softmax alpha ->
//     n_hat = sum alpha*tok -> logits = tok.n_hat + bias -> softmax -> out
// ---------------------------------------------------------------------------
__global__ __launch_bounds__(256) void k_final(
    const unsigned short* __restrict__ tokpad, const unsigned short* __restrict__ c2o,
    const float* __restrict__ h_t, const float* __restrict__ c3w,
    const float* __restrict__ c3b, const float* __restrict__ biasg,
    float* __restrict__ out)
{
  __shared__ float Lf[71 * 65];
  __shared__ float a_lds[2048];
  __shared__ float l_lds[2048];
  __shared__ float red[256];
  __shared__ float nred[512];
  __shared__ float nhat[128];
  __shared__ float ht[64];
  __shared__ float c3[512];
  int b = blockIdx.x, tid = threadIdx.x, lane = tid & 63, wave = tid >> 6;
  if (tid < 64) ht[tid] = h_t[b * 64 + tid];
  for (int i = tid; i < 512; i += 256) c3[i] = c3w[i];
  float c3bias = c3b[0];
  __syncthreads();
  // ---- pass 1: a_logits via normalized features + conv3 (tiles of 64 l) ----
  for (int tile = 0; tile < 32; ++tile) {
    int lt = tile << 6;
    for (int i0 = wave; i0 < 71; i0 += 4) {
      int l = lt - 3 + i0;
      float v = 0.f;
      if (l >= 0 && l < L_) v = bf2f(c2o[((size_t)b * L_ + l) * 64 + lane]) * ht[lane];
      float ss = v * v;
      #pragma unroll
      for (int msk = 1; msk < 64; msk <<= 1) ss += __shfl_xor(ss, msk);
      Lf[i0 * 65 + lane] = v * rsqrtf(ss + 1e-12f);
    }
    __syncthreads();
    {
      int u = lane, part = wave;
      float p = 0.f;
      #pragma unroll
      for (int w = 0; w < 8; ++w)
        #pragma unroll
        for (int cc = 0; cc < 16; ++cc) {
          int c = part * 16 + cc;
          p += Lf[(u + w) * 65 + c] * c3[w * 64 + c];
        }
      red[tid] = p;
    }
    __syncthreads();
    if (tid < 64) a_lds[lt + tid] = red[tid] + red[64 + tid] + red[128 + tid] + red[192 + tid] + c3bias;
    __syncthreads();
  }
  // ---- pass 2: softmax alpha over 2048 ----
  {
    float mx = -1e30f;
    for (int i = tid; i < 2048; i += 256) mx = fmaxf(mx, a_lds[i]);
    #pragma unroll
    for (int msk = 1; msk < 64; msk <<= 1) mx = fmaxf(mx, __shfl_xor(mx, msk));
    if (lane == 0) red[wave] = mx;
    __syncthreads();
    mx = fmaxf(fmaxf(red[0], red[1]), fmaxf(red[2], red[3]));
    float sm = 0.f;
    for (int i = tid; i < 2048; i += 256) sm += __expf(a_lds[i] - mx);
    #pragma unroll
    for (int msk = 1; msk < 64; msk <<= 1) sm += __shfl_xor(sm, msk);
    __syncthreads();
    if (lane == 0) red[wave] = sm;
    __syncthreads();
    sm = red[0] + red[1] + red[2] + red[3];
    float inv = 1.f / sm;
    for (int i = tid; i < 2048; i += 256) a_lds[i] = __expf(a_lds[i] - mx) * inv;
    __syncthreads();
  }
  // ---- pass 3: n_hat[128] = sum_l alpha_l * tok[l][:] ----
  {
    int d2 = tid & 63, g = tid >> 6;
    float ax = 0.f, ay = 0.f;
    for (int l = g; l < L_; l += 4) {
      unsigned int uu = *(const unsigned int*)&tokpad[((size_t)b * LP + PAD + l) * 128 + d2 * 2];
      float al = a_lds[l];
      ax += al * bf2f((unsigned short)(uu & 0xffffu));
      ay += al * bf2f((unsigned short)(uu >> 16));
    }
    nred[g * 128 + d2 * 2] = ax;
    nred[g * 128 + d2 * 2 + 1] = ay;
    __syncthreads();
    if (tid < 128) nhat[tid] = nred[tid] + nred[128 + tid] + nred[256 + tid] + nred[384 + tid];
    __syncthreads();
  }
  // ---- pass 4: logits = tok . n_hat + bias ----
  for (int li = 0; li < 8; ++li) {
    int l = li * 256 + tid;
    const uint4* rowp = (const uint4*)&tokpad[((size_t)b * LP + PAD + l) * 128];
    float s = 0.f;
    #pragma unroll
    for (int jj = 0; jj < 16; ++jj) {
      uint4 uu = rowp[jj];
      s += bf2f((unsigned short)(uu.x & 0xffffu)) * nhat[jj*8+0]
         + bf2f((unsigned short)(uu.x >> 16))     * nhat[jj*8+1]
         + bf2f((unsigned short)(uu.y & 0xffffu)) * nhat[jj*8+2]
         + bf2f((unsigned short)(uu.y >> 16))     * nhat[jj*8+3]
         + bf2f((unsigned short)(uu.z & 0xffffu)) * nhat[jj*8+4]
         + bf2f((unsigned short)(uu.z >> 16))     * nhat[jj*8+5]
         + bf2f((unsigned short)(uu.w & 0xffffu)) * nhat[jj*8+6]
         + bf2f((unsigned short)(uu.w >> 16))     * nhat[jj*8+7];
    }
    l_lds[l] = s + biasg[b * L_ + l];
  }
  __syncthreads();
  // ---- pass 5: final softmax -> out ----
  {
    float mx = -1e30f;
    for (int i = tid; i < 2048; i += 256) mx = fmaxf(mx, l_lds[i]);
    #pragma unroll
    for (int msk = 1; msk < 64; msk <<= 1) mx = fmaxf(mx, __shfl_xor(mx, msk));
    __syncthreads();
    if (lane == 0) red[wave] = mx;
    __syncthreads();
    mx = fmaxf(fmaxf(red[0], red[1]), fmaxf(red[2], red[3]));
    float sm = 0.f;
    for (int i = tid; i < 2048; i += 256) sm += __expf(l_lds[i] - mx);
    #pragma unroll
    for (int msk = 1; msk < 64; msk <<= 1) sm += __shfl_xor(sm, msk);
    __syncthreads();
    if (lane == 0) red[wave] = sm;
    __syncthreads();
    sm = red[0] + red[1] + red[2] + red[3];
    float inv = 1.f / sm;
    for (int i = tid; i < 2048; i += 256) out[b * L_ + i] = __expf(l_lds[i] - mx) * inv;
  }
}

// ---------------------------------------------------------------------------
extern "C" void kernel_launch(void* const* d_in, const int* in_sizes, int n_in,
                              void* d_out, int out_size, void* d_ws, size_t ws_size,
                              hipStream_t stream) {
  const int*   code = (const int*)d_in[0];
  const float* E    = (const float*)d_in[1];
  const float* bt   = (const float*)d_in[2];
  const float* Wx   = (const float*)d_in[3];
  const float* Wh   = (const float*)d_in[4];
  const float* bg   = (const float*)d_in[5];
  const float* c1w  = (const float*)d_in[6];
  const float* c1b  = (const float*)d_in[7];
  const float* c2w  = (const float*)d_in[8];
  const float* c2b  = (const float*)d_in[9];
  const float* c3w  = (const float*)d_in[10];
  const float* c3b  = (const float*)d_in[11];
  char* ws = (char*)d_ws;
  unsigned short* tokpad = (unsigned short*)(ws);               // 33,685,504 B
  unsigned short* l1pad  = (unsigned short*)(ws + 33685504);    // 16,842,752 B
  unsigned short* xprojT = (unsigned short*)(ws + 50528256);    // 50,331,648 B
  unsigned short* c2o    = (unsigned short*)(ws + 100859904);   // 16,777,216 B
  unsigned short* WxT    = (unsigned short*)(ws + 117637120);   //     49,152 B
  unsigned short* c1wT   = (unsigned short*)(ws + 117686272);   //    131,072 B
  unsigned short* c2wT   = (unsigned short*)(ws + 117817344);   //     65,536 B
  float*          htp    = (float*)(ws + 117882880);            //     16,384 B
  float*          biasg  = (float*)(ws + 117899264);            //    524,288 B
  unsigned short* WhTg   = (unsigned short*)(ws + 118423552);   //     24,576 B
  // total ws use: 118,448,128 B

  k_prep <<<9280, 256, 0, stream>>>(code, E, bt, Wx, c1w, c2w, Wh,
                                    tokpad, l1pad, WxT, c1wT, c2wT, biasg, WhTg);
  k_xproj<<<1024, 256, 0, stream>>>(tokpad, WxT, bg, xprojT);
  k_scan <<<4, 256, 0, stream>>>(xprojT, WhTg, bg, htp);
  k_conv1<<<1024, 256, 0, stream>>>(tokpad, c1wT, c1b, l1pad);
  k_conv2<<<1024, 256, 0, stream>>>(l1pad, c2wT, c2b, c2o);
  k_final<<<64, 256, 0, stream>>>(tokpad, c2o, htp, c3w, c3b, biasg, (float*)d_out);
}

// Round 10
// 1593.921 us; speedup vs baseline: 1.3427x; 1.3371x over previous
//
#include <hip/hip_runtime.h>

#define B_ 64
#define L_ 2048
#define D_ 128
#define LP 2056   // padded rows per batch (3 left, 5 right incl. alignment)
#define PAD 3     // SAME-pad left for W=8

typedef __attribute__((ext_vector_type(8))) short short8;
typedef __attribute__((ext_vector_type(4))) float f32x4;
typedef __attribute__((ext_vector_type(4))) unsigned short us4;

static __device__ __forceinline__ float bf2f(unsigned short u) {
  return __uint_as_float(((unsigned int)u) << 16);
}
static __device__ __forceinline__ unsigned short f2bf(float f) {
  unsigned int x = __float_as_uint(f);
  unsigned int r = (x + 0x7fffu + ((x >> 16) & 1u)) >> 16;  // RNE
  return (unsigned short)r;
}

// ---------------------------------------------------------------------------
// K0: gather tok -> bf16 padded [B,LP,128]; gather bias; transpose weights.
// ---------------------------------------------------------------------------
__global__ __launch_bounds__(256) void k_prep(
    const int* __restrict__ code, const float* __restrict__ E,
    const float* __restrict__ bias_table, const float* __restrict__ Wx,
    const float* __restrict__ c1w, const float* __restrict__ c2w,
    unsigned short* __restrict__ tokpad,
    unsigned short* __restrict__ WxT, unsigned short* __restrict__ c1wT,
    unsigned short* __restrict__ c2wT, float* __restrict__ biasg)
{
  int id = blockIdx.x * 256 + threadIdx.x;
  const int N0 = B_ * LP * 16;            // tokpad in uint4 (8 bf16) chunks
  if (id < N0) {
    int b = id / (LP * 16); int rem = id % (LP * 16);
    int row = rem >> 4, c8 = rem & 15;
    uint4 o = {0u,0u,0u,0u};
    if (row >= PAD && row < PAD + L_) {
      int cd = code[b * L_ + (row - PAD)];
      const float4* e = (const float4*)(E + (size_t)cd * D_ + c8 * 8);
      float4 e0 = e[0], e1 = e[1];
      o.x = f2bf(e0.x) | ((unsigned int)f2bf(e0.y) << 16);
      o.y = f2bf(e0.z) | ((unsigned int)f2bf(e0.w) << 16);
      o.z = f2bf(e1.x) | ((unsigned int)f2bf(e1.y) << 16);
      o.w = f2bf(e1.z) | ((unsigned int)f2bf(e1.w) << 16);
    }
    ((uint4*)tokpad)[id] = o;
    return;
  }
  id -= N0;
  const int N2 = B_ * L_;
  if (id < N2) { biasg[id] = bias_table[code[id]]; return; }
  id -= N2;
  const int N3 = 192 * 128;               // WxT[c][d]
  if (id < N3) { int c = id >> 7, d = id & 127; WxT[id] = f2bf(Wx[d * 192 + c]); return; }
  id -= N3;
  const int N4 = 8 * 64 * 128;            // c1wT[w][c][d]
  if (id < N4) {
    int w = id >> 13, c = (id >> 7) & 63, d = id & 127;
    c1wT[id] = f2bf(c1w[(w * 128 + d) * 64 + c]); return;
  }
  id -= N4;
  const int N5 = 8 * 64 * 64;             // c2wT[w][c][d]
  if (id < N5) {
    int w = id >> 12, c = (id >> 6) & 63, d = id & 63;
    c2wT[id] = f2bf(c2w[(w * 64 + d) * 64 + c]);
  }
}

// ---------------------------------------------------------------------------
// K1: x_proj = tok @ Wx + b_gru[0] -> bf16 TRANSPOSED [B,192,L]
// ---------------------------------------------------------------------------
__global__ __launch_bounds__(256) void k_xproj(
    const unsigned short* __restrict__ tokpad, const unsigned short* __restrict__ WxT,
    const float* __restrict__ bg, unsigned short* __restrict__ xprojT)
{
  __shared__ __align__(16) unsigned short At[128 * 136];
  __shared__ __align__(16) unsigned short Bt[192 * 136];
  int b = blockIdx.x >> 4;
  int l0 = (blockIdx.x & 15) << 7;
  int tid = threadIdx.x;
  for (int i = tid; i < 128 * 16; i += 256) {
    int row = i >> 4, c8 = i & 15;
    uint4 v = ((const uint4*)tokpad)[(b * LP + PAD + l0 + row) * 16 + c8];
    *((uint4*)&At[row * 136 + c8 * 8]) = v;
  }
  for (int i = tid; i < 192 * 16; i += 256) {
    int row = i >> 4, c8 = i & 15;
    uint4 v = ((const uint4*)WxT)[i];
    *((uint4*)&Bt[row * 136 + c8 * 8]) = v;
  }
  __syncthreads();
  int wave = tid >> 6, lane = tid & 63;
  int m = lane & 15, q = lane >> 4;
  f32x4 acc[2][12];
  #pragma unroll
  for (int mt = 0; mt < 2; ++mt)
    #pragma unroll
    for (int nt = 0; nt < 12; ++nt) acc[mt][nt] = (f32x4){0.f,0.f,0.f,0.f};
  #pragma unroll
  for (int ks = 0; ks < 4; ++ks) {
    int kof = ks * 32 + q * 8;
    short8 a[2], bb[12];
    #pragma unroll
    for (int mt = 0; mt < 2; ++mt)
      a[mt] = *(const short8*)&At[(wave * 32 + mt * 16 + m) * 136 + kof];
    #pragma unroll
    for (int nt = 0; nt < 12; ++nt)
      bb[nt] = *(const short8*)&Bt[(nt * 16 + m) * 136 + kof];
    #pragma unroll
    for (int mt = 0; mt < 2; ++mt)
      #pragma unroll
      for (int nt = 0; nt < 12; ++nt)
        acc[mt][nt] = __builtin_amdgcn_mfma_f32_16x16x32_bf16(a[mt], bb[nt], acc[mt][nt], 0, 0, 0);
  }
  #pragma unroll
  for (int mt = 0; mt < 2; ++mt) {
    int lrow = l0 + wave * 32 + mt * 16 + q * 4;
    #pragma unroll
    for (int nt = 0; nt < 12; ++nt) {
      int c = nt * 16 + m;                 // C col = lane&15
      float b0 = bg[c];
      us4 val;
      val.x = f2bf(acc[mt][nt][0] + b0);
      val.y = f2bf(acc[mt][nt][1] + b0);
      val.z = f2bf(acc[mt][nt][2] + b0);
      val.w = f2bf(acc[mt][nt][3] + b0);
      *((us4*)&xprojT[((size_t)b * 192 + c) * L_ + lrow]) = val;
    }
  }
}

// ---------------------------------------------------------------------------
// K2 (fused): blocks 0..63 = R6 GRU scan (1004 us, best measured structure);
// blocks 64..255 = conv1+conv2 fused with halo recompute (l1 lives only in
// LDS, bf16-rounded identically to the old global round-trip). No cross-block
// dependency of any kind -> no grid sync needed; conv runs on the 192 CUs the
// scan leaves idle, hiding its entire cost under the scan's 1 ms.
// ---------------------------------------------------------------------------
#define BARRIER() asm volatile("s_waitcnt lgkmcnt(0)\n\ts_barrier" ::: "memory")

__global__ __launch_bounds__(192)
__attribute__((amdgpu_waves_per_eu(1, 1)))
void k_fused(
    const unsigned short* __restrict__ xprojT, const float* __restrict__ Wh,
    const float* __restrict__ bg, float* __restrict__ h_t,
    const unsigned short* __restrict__ tokpad,
    const unsigned short* __restrict__ c1wT, const float* __restrict__ c1b,
    const unsigned short* __restrict__ c2wT, const float* __restrict__ c2b,
    unsigned short* __restrict__ c2o)
{
  // 79488 B shared pool. Scan carves 192 floats; conv carves At/l1buf/Bw.
  // Size doubles as the occupancy backstop (<=2 WG/CU) for the scan's
  // waves_per_eu(1,1) register budget (R5-verified mechanism).
  __shared__ __align__(16) unsigned short pool[39744];
  int bid = blockIdx.x;
  int tid = threadIdx.x;

  if (bid < 64) {
    // ================= GRU scan (R6 structure, verbatim) =================
    float* h_lds = (float*)pool;
    float* s_z   = (float*)pool + 64;
    float* s_r   = (float*)pool + 128;

    int b = bid;
    int wave = tid >> 6, j = tid & 63;
    int o = wave * 64 + j;                // output column 0..191

#define DECL_W(i) float4 w##i = {Wh[(4*i+0)*192+o], Wh[(4*i+1)*192+o], \
                                 Wh[(4*i+2)*192+o], Wh[(4*i+3)*192+o]};
    DECL_W(0)  DECL_W(1)  DECL_W(2)  DECL_W(3)
    DECL_W(4)  DECL_W(5)  DECL_W(6)  DECL_W(7)
    DECL_W(8)  DECL_W(9)  DECL_W(10) DECL_W(11)
    DECL_W(12) DECL_W(13) DECL_W(14) DECL_W(15)
#undef DECL_W
#define OPAQ(i) asm volatile("" : "+v"(w##i.x), "+v"(w##i.y), "+v"(w##i.z), "+v"(w##i.w));
    OPAQ(0)  OPAQ(1)  OPAQ(2)  OPAQ(3)
    OPAQ(4)  OPAQ(5)  OPAQ(6)  OPAQ(7)
    OPAQ(8)  OPAQ(9)  OPAQ(10) OPAQ(11)
    OPAQ(12) OPAQ(13) OPAQ(14) OPAQ(15)
#undef OPAQ
    float bias = bg[192 + o];             // b_gru[1][o]

    if (wave == 2) h_lds[j] = 0.f;
    float h_old = 0.f;

    const unsigned short* xc = xprojT + ((size_t)b * 192 + o) * L_;
    const float4* hl4 = (const float4*)h_lds;

    uint4 cur0 = ((const uint4*)xc)[0];
    uint4 cur1 = ((const uint4*)xc)[1];

#define STEP(XU) { \
    BARRIER(); \
    float a0 = bias, a1 = 0.f, a2 = 0.f, a3 = 0.f; \
    { float4 h4; \
      h4 = hl4[0];  a0 = fmaf(h4.x, w0.x, a0);  a1 = fmaf(h4.y, w0.y, a1);  a2 = fmaf(h4.z, w0.z, a2);  a3 = fmaf(h4.w, w0.w, a3); \
      h4 = hl4[1];  a0 = fmaf(h4.x, w1.x, a0);  a1 = fmaf(h4.y, w1.y, a1);  a2 = fmaf(h4.z, w1.z, a2);  a3 = fmaf(h4.w, w1.w, a3); \
      h4 = hl4[2];  a0 = fmaf(h4.x, w2.x, a0);  a1 = fmaf(h4.y, w2.y, a1);  a2 = fmaf(h4.z, w2.z, a2);  a3 = fmaf(h4.w, w2.w, a3); \
      h4 = hl4[3];  a0 = fmaf(h4.x, w3.x, a0);  a1 = fmaf(h4.y, w3.y, a1);  a2 = fmaf(h4.z, w3.z, a2);  a3 = fmaf(h4.w, w3.w, a3); \
      h4 = hl4[4];  a0 = fmaf(h4.x, w4.x, a0);  a1 = fmaf(h4.y, w4.y, a1);  a2 = fmaf(h4.z, w4.z, a2);  a3 = fmaf(h4.w, w4.w, a3); \
      h4 = hl4[5];  a0 = fmaf(h4.x, w5.x, a0);  a1 = fmaf(h4.y, w5.y, a1);  a2 = fmaf(h4.z, w5.z, a2);  a3 = fmaf(h4.w, w5.w, a3); \
      h4 = hl4[6];  a0 = fmaf(h4.x, w6.x, a0);  a1 = fmaf(h4.y, w6.y, a1);  a2 = fmaf(h4.z, w6.z, a2);  a3 = fmaf(h4.w, w6.w, a3); \
      h4 = hl4[7];  a0 = fmaf(h4.x, w7.x, a0);  a1 = fmaf(h4.y, w7.y, a1);  a2 = fmaf(h4.z, w7.z, a2);  a3 = fmaf(h4.w, w7.w, a3); \
      h4 = hl4[8];  a0 = fmaf(h4.x, w8.x, a0);  a1 = fmaf(h4.y, w8.y, a1);  a2 = fmaf(h4.z, w8.z, a2);  a3 = fmaf(h4.w, w8.w, a3); \
      h4 = hl4[9];  a0 = fmaf(h4.x, w9.x, a0);  a1 = fmaf(h4.y, w9.y, a1);  a2 = fmaf(h4.z, w9.z, a2);  a3 = fmaf(h4.w, w9.w, a3); \
      h4 = hl4[10]; a0 = fmaf(h4.x, w10.x, a0); a1 = fmaf(h4.y, w10.y, a1); a2 = fmaf(h4.z, w10.z, a2); a3 = fmaf(h4.w, w10.w, a3); \
      h4 = hl4[11]; a0 = fmaf(h4.x, w11.x, a0); a1 = fmaf(h4.y, w11.y, a1); a2 = fmaf(h4.z, w11.z, a2); a3 = fmaf(h4.w, w11.w, a3); \
      h4 = hl4[12]; a0 = fmaf(h4.x, w12.x, a0); a1 = fmaf(h4.y, w12.y, a1); a2 = fmaf(h4.z, w12.z, a2); a3 = fmaf(h4.w, w12.w, a3); \
      h4 = hl4[13]; a0 = fmaf(h4.x, w13.x, a0); a1 = fmaf(h4.y, w13.y, a1); a2 = fmaf(h4.z, w13.z, a2); a3 = fmaf(h4.w, w13.w, a3); \
      h4 = hl4[14]; a0 = fmaf(h4.x, w14.x, a0); a1 = fmaf(h4.y, w14.y, a1); a2 = fmaf(h4.z, w14.z, a2); a3 = fmaf(h4.w, w14.w, a3); \
      h4 = hl4[15]; a0 = fmaf(h4.x, w15.x, a0); a1 = fmaf(h4.y, w15.y, a1); a2 = fmaf(h4.z, w15.z, a2); a3 = fmaf(h4.w, w15.w, a3); } \
    float s = (a0 + a1) + (a2 + a3); \
    float xv = bf2f((unsigned short)(XU)); \
    if (wave == 0)      s_z[j] = 1.f / (1.f + __expf(-(xv + s))); \
    else if (wave == 1) s_r[j] = 1.f / (1.f + __expf(-(xv + s))); \
    BARRIER(); \
    if (wave == 2) { \
      float z = s_z[j], r = s_r[j]; \
      float e2 = __expf(-2.f * (xv + r * s)); \
      float hh = fmaf(2.f, __frcp_rn(1.f + e2), -1.f); \
      h_old = z * h_old + (1.f - z) * hh; \
      h_lds[j] = h_old; \
    } }

#define STEP8(C) \
    STEP(C.x & 0xffffu) STEP(C.x >> 16) \
    STEP(C.y & 0xffffu) STEP(C.y >> 16) \
    STEP(C.z & 0xffffu) STEP(C.z >> 16) \
    STEP(C.w & 0xffffu) STEP(C.w >> 16)

    for (int t0 = 0; t0 < L_; t0 += 16) {
      int tn = (t0 + 16 < L_) ? t0 + 16 : t0;
      const uint4* pn = (const uint4*)(xc + tn);
      uint4 nxt0 = pn[0];
      uint4 nxt1 = pn[1];
      STEP8(cur0)
      STEP8(cur1)
      cur0 = nxt0; cur1 = nxt1;
    }
#undef STEP8
#undef STEP
    if (wave == 2) h_t[b * 64 + j] = h_old;
    return;
  }

  // ================= fused conv1+conv2 (halo recompute) =================
  unsigned short* At    = pool;           // 152 x 136 shorts = 41344 B
  unsigned short* l1buf = pool + 20672;   // 144 x 72  shorts = 20736 B
  unsigned short* Bw    = pool + 31040;   //  64 x 136 shorts = 17408 B
  int wv = tid >> 6, lane = tid & 63;
  int m = lane & 15, q = lane >> 4;

  for (int job = bid - 64; job < 1024; job += 192) {
    int b = job >> 4;
    int l0 = (job & 15) << 7;
    __syncthreads();                      // prev job fully consumed
    // stage tokpad rows [l0-3, l0+148] (clamped; junk feeds only zeroed rows)
    for (int i = tid; i < 152 * 16; i += 192) {
      int row = i >> 4, c8 = i & 15;
      int p = l0 - 3 + row;
      p = p < 0 ? 0 : (p > 2055 ? 2055 : p);
      *((uint4*)&At[row * 136 + c8 * 8]) = ((const uint4*)tokpad)[(b * LP + p) * 16 + c8];
    }
    // ---- conv1: l1 rows [l0-3, l0+140] (9 M-tiles of 16), K=128 ----
    f32x4 acc[3][4];
    #pragma unroll
    for (int mt = 0; mt < 3; ++mt)
      #pragma unroll
      for (int nt = 0; nt < 4; ++nt) acc[mt][nt] = (f32x4){0.f,0.f,0.f,0.f};
    for (int w8 = 0; w8 < 8; ++w8) {
      __syncthreads();
      for (int i = tid; i < 64 * 16; i += 192) {
        int row = i >> 4, c8 = i & 15;
        *((uint4*)&Bw[row * 136 + c8 * 8]) = ((const uint4*)c1wT)[(w8 * 64 + row) * 16 + c8];
      }
      __syncthreads();
      #pragma unroll
      for (int ks = 0; ks < 4; ++ks) {
        int kof = ks * 32 + q * 8;
        short8 a[3], bb[4];
        #pragma unroll
        for (int mt = 0; mt < 3; ++mt) {
          int tl = wv + 3 * mt;
          a[mt] = *(const short8*)&At[(tl * 16 + m + w8) * 136 + kof];
        }
        #pragma unroll
        for (int nt = 0; nt < 4; ++nt)
          bb[nt] = *(const short8*)&Bw[(nt * 16 + m) * 136 + kof];
        #pragma unroll
        for (int mt = 0; mt < 3; ++mt)
          #pragma unroll
          for (int nt = 0; nt < 4; ++nt)
            acc[mt][nt] = __builtin_amdgcn_mfma_f32_16x16x32_bf16(a[mt], bb[nt], acc[mt][nt], 0, 0, 0);
      }
    }
    // store l1 (relu+bias, bf16 — identical rounding to old global path)
    #pragma unroll
    for (int mt = 0; mt < 3; ++mt) {
      int tl = wv + 3 * mt;
      #pragma unroll
      for (int nt = 0; nt < 4; ++nt) {
        int c = nt * 16 + m;
        float bs = c1b[c];
        #pragma unroll
        for (int r = 0; r < 4; ++r) {
          float v = fmaxf(acc[mt][nt][r] + bs, 0.f);
          l1buf[(tl * 16 + q * 4 + r) * 72 + c] = f2bf(v);
        }
      }
    }
    __syncthreads();
    // zero l1 rows outside [0, 2047] (SAME-pad semantics of conv2 input)
    for (int i2 = tid; i2 < 135 * 8; i2 += 192) {
      int i = i2 >> 3, c8 = i2 & 7;
      int jrow = l0 - 3 + i;
      if (jrow < 0 || jrow > 2047) {
        uint4 z4 = {0u,0u,0u,0u};
        *((uint4*)&l1buf[i * 72 + c8 * 8]) = z4;
      }
    }
    // ---- conv2: out rows [l0, l0+127] (8 M-tiles), K=64 ----
    f32x4 acc2[3][4];
    #pragma unroll
    for (int mt = 0; mt < 3; ++mt)
      #pragma unroll
      for (int nt = 0; nt < 4; ++nt) acc2[mt][nt] = (f32x4){0.f,0.f,0.f,0.f};
    for (int w8 = 0; w8 < 8; ++w8) {
      __syncthreads();                    // first iter: zero-pass+l1 visible
      for (int i = tid; i < 64 * 8; i += 192) {
        int row = i >> 3, c8 = i & 7;
        *((uint4*)&Bw[row * 72 + c8 * 8]) = ((const uint4*)c2wT)[(w8 * 64 + row) * 8 + c8];
      }
      __syncthreads();
      #pragma unroll
      for (int ks = 0; ks < 2; ++ks) {
        int kof = ks * 32 + q * 8;
        short8 a[3], bb[4];
        #pragma unroll
        for (int mt = 0; mt < 3; ++mt) {
          int tl = wv + 3 * mt;
          if (tl < 8)
            a[mt] = *(const short8*)&l1buf[(tl * 16 + m + w8) * 72 + kof];
        }
        #pragma unroll
        for (int nt = 0; nt < 4; ++nt)
          bb[nt] = *(const short8*)&Bw[(nt * 16 + m) * 72 + kof];
        #pragma unroll
        for (int mt = 0; mt < 3; ++mt) {
          int tl = wv + 3 * mt;
          if (tl < 8)
            #pragma unroll
            for (int nt = 0; nt < 4; ++nt)
              acc2[mt][nt] = __builtin_amdgcn_mfma_f32_16x16x32_bf16(a[mt], bb[nt], acc2[mt][nt], 0, 0, 0);
        }
      }
    }
    // epilogue: c2o[B,L,64] bf16 (+c2b)
    #pragma unroll
    for (int mt = 0; mt < 3; ++mt) {
      int tl = wv + 3 * mt;
      if (tl < 8) {
        #pragma unroll
        for (int nt = 0; nt < 4; ++nt) {
          int c = nt * 16 + m;
          float bs = c2b[c];
          #pragma unroll
          for (int r = 0; r < 4; ++r)
            c2o[(size_t)(b * L_ + l0 + tl * 16 + q * 4 + r) * 64 + c] = f2bf(acc2[mt][nt][r] + bs);
        }
      }
    }
  }
}

// ---------------------------------------------------------------------------
// K5: per-batch tail: L2=c2o*h_t -> l2norm -> conv3 -> softmax alpha ->
//     n_hat = sum alpha*tok -> logits = tok.n_hat + bias -> softmax -> out
// ---------------------------------------------------------------------------
__global__ __launch_bounds__(256) void k_final(
    const unsigned short* __restrict__ tokpad, const unsigned short* __restrict__ c2o,
    const float* __restrict__ h_t, const float* __restrict__ c3w,
    const float* __restrict__ c3b, const float* __restrict__ biasg,
    float* __restrict__ out)
{
  __shared__ float Lf[71 * 65];
  __shared__ float a_lds[2048];
  __shared__ float l_lds[2048];
  __shared__ float red[256];
  __shared__ float nred[512];
  __shared__ float nhat[128];
  __shared__ float ht[64];
  __shared__ float c3[512];
  int b = blockIdx.x, tid = threadIdx.x, lane = tid & 63, wave = tid >> 6;
  if (tid < 64) ht[tid] = h_t[b * 64 + tid];
  for (int i = tid; i < 512; i += 256) c3[i] = c3w[i];
  float c3bias = c3b[0];
  __syncthreads();
  // ---- pass 1: a_logits via normalized features + conv3 (tiles of 64 l) ----
  for (int tile = 0; tile < 32; ++tile) {
    int lt = tile << 6;
    for (int i0 = wave; i0 < 71; i0 += 4) {
      int l = lt - 3 + i0;
      float v = 0.f;
      if (l >= 0 && l < L_) v = bf2f(c2o[((size_t)b * L_ + l) * 64 + lane]) * ht[lane];
      float ss = v * v;
      #pragma unroll
      for (int msk = 1; msk < 64; msk <<= 1) ss += __shfl_xor(ss, msk);
      Lf[i0 * 65 + lane] = v * rsqrtf(ss + 1e-12f);
    }
    __syncthreads();
    {
      int u = lane, part = wave;
      float p = 0.f;
      #pragma unroll
      for (int w = 0; w < 8; ++w)
        #pragma unroll
        for (int cc = 0; cc < 16; ++cc) {
          int c = part * 16 + cc;
          p += Lf[(u + w) * 65 + c] * c3[w * 64 + c];
        }
      red[tid] = p;
    }
    __syncthreads();
    if (tid < 64) a_lds[lt + tid] = red[tid] + red[64 + tid] + red[128 + tid] + red[192 + tid] + c3bias;
    __syncthreads();
  }
  // ---- pass 2: softmax alpha over 2048 ----
  {
    float mx = -1e30f;
    for (int i = tid; i < 2048; i += 256) mx = fmaxf(mx, a_lds[i]);
    #pragma unroll
    for (int msk = 1; msk < 64; msk <<= 1) mx = fmaxf(mx, __shfl_xor(mx, msk));
    if (lane == 0) red[wave] = mx;
    __syncthreads();
    mx = fmaxf(fmaxf(red[0], red[1]), fmaxf(red[2], red[3]));
    float sm = 0.f;
    for (int i = tid; i < 2048; i += 256) sm += __expf(a_lds[i] - mx);
    #pragma unroll
    for (int msk = 1; msk < 64; msk <<= 1) sm += __shfl_xor(sm, msk);
    __syncthreads();
    if (lane == 0) red[wave] = sm;
    __syncthreads();
    sm = red[0] + red[1] + red[2] + red[3];
    float inv = 1.f / sm;
    for (int i = tid; i < 2048; i += 256) a_lds[i] = __expf(a_lds[i] - mx) * inv;
    __syncthreads();
  }
  // ---- pass 3: n_hat[128] = sum_l alpha_l * tok[l][:] ----
  {
    int d2 = tid & 63, g = tid >> 6;
    float ax = 0.f, ay = 0.f;
    for (int l = g; l < L_; l += 4) {
      unsigned int uu = *(const unsigned int*)&tokpad[((size_t)b * LP + PAD + l) * 128 + d2 * 2];
      float al = a_lds[l];
      ax += al * bf2f((unsigned short)(uu & 0xffffu));
      ay += al * bf2f((unsigned short)(uu >> 16));
    }
    nred[g * 128 + d2 * 2] = ax;
    nred[g * 128 + d2 * 2 + 1] = ay;
    __syncthreads();
    if (tid < 128) nhat[tid] = nred[tid] + nred[128 + tid] + nred[256 + tid] + nred[384 + tid];
    __syncthreads();
  }
  // ---- pass 4: logits = tok . n_hat + bias ----
  for (int li = 0; li < 8; ++li) {
    int l = li * 256 + tid;
    const uint4* rowp = (const uint4*)&tokpad[((size_t)b * LP + PAD + l) * 128];
    float s = 0.f;
    #pragma unroll
    for (int jj = 0; jj < 16; ++jj) {
      uint4 uu = rowp[jj];
      s += bf2f((unsigned short)(uu.x & 0xffffu)) * nhat[jj*8+0]
         + bf2f((unsigned short)(uu.x >> 16))     * nhat[jj*8+1]
         + bf2f((unsigned short)(uu.y & 0xffffu)) * nhat[jj*8+2]
         + bf2f((unsigned short)(uu.y >> 16))     * nhat[jj*8+3]
         + bf2f((unsigned short)(uu.z & 0xffffu)) * nhat[jj*8+4]
         + bf2f((unsigned short)(uu.z >> 16))     * nhat[jj*8+5]
         + bf2f((unsigned short)(uu.w & 0xffffu)) * nhat[jj*8+6]
         + bf2f((unsigned short)(uu.w >> 16))     * nhat[jj*8+7];
    }
    l_lds[l] = s + biasg[b * L_ + l];
  }
  __syncthreads();
  // ---- pass 5: final softmax -> out ----
  {
    float mx = -1e30f;
    for (int i = tid; i < 2048; i += 256) mx = fmaxf(mx, l_lds[i]);
    #pragma unroll
    for (int msk = 1; msk < 64; msk <<= 1) mx = fmaxf(mx, __shfl_xor(mx, msk));
    __syncthreads();
    if (lane == 0) red[wave] = mx;
    __syncthreads();
    mx = fmaxf(fmaxf(red[0], red[1]), fmaxf(red[2], red[3]));
    float sm = 0.f;
    for (int i = tid; i < 2048; i += 256) sm += __expf(l_lds[i] - mx);
    #pragma unroll
    for (int msk = 1; msk < 64; msk <<= 1) sm += __shfl_xor(sm, msk);
    __syncthreads();
    if (lane == 0) red[wave] = sm;
    __syncthreads();
    sm = red[0] + red[1] + red[2] + red[3];
    float inv = 1.f / sm;
    for (int i = tid; i < 2048; i += 256) out[b * L_ + i] = __expf(l_lds[i] - mx) * inv;
  }
}

// ---------------------------------------------------------------------------
extern "C" void kernel_launch(void* const* d_in, const int* in_sizes, int n_in,
                              void* d_out, int out_size, void* d_ws, size_t ws_size,
                              hipStream_t stream) {
  const int*   code = (const int*)d_in[0];
  const float* E    = (const float*)d_in[1];
  const float* bt   = (const float*)d_in[2];
  const float* Wx   = (const float*)d_in[3];
  const float* Wh   = (const float*)d_in[4];
  const float* bg   = (const float*)d_in[5];
  const float* c1w  = (const float*)d_in[6];
  const float* c1b  = (const float*)d_in[7];
  const float* c2w  = (const float*)d_in[8];
  const float* c2b  = (const float*)d_in[9];
  const float* c3w  = (const float*)d_in[10];
  const float* c3b  = (const float*)d_in[11];
  char* ws = (char*)d_ws;
  unsigned short* tokpad = (unsigned short*)(ws);               // 33,685,504 B
  unsigned short* xprojT = (unsigned short*)(ws + 50528256);    // 50,331,648 B
  unsigned short* c2o    = (unsigned short*)(ws + 100859904);   // 16,777,216 B
  unsigned short* WxT    = (unsigned short*)(ws + 117637120);   //     49,152 B
  unsigned short* c1wT   = (unsigned short*)(ws + 117686272);   //    131,072 B
  unsigned short* c2wT   = (unsigned short*)(ws + 117817344);   //     65,536 B
  float*          htp    = (float*)(ws + 117882880);            //     16,384 B
  float*          biasg  = (float*)(ws + 117899264);            //    524,288 B
  // total ws use: 118,423,552 B

  k_prep <<<9216, 256, 0, stream>>>(code, E, bt, Wx, c1w, c2w, tokpad, WxT, c1wT, c2wT, biasg);
  k_xproj<<<1024, 256, 0, stream>>>(tokpad, WxT, bg, xprojT);
  k_fused<<<256, 192, 0, stream>>>(xprojT, Wh, bg, htp, tokpad, c1wT, c1b, c2wT, c2b, c2o);
  k_final<<<64, 256, 0, stream>>>(tokpad, c2o, htp, c3w, c3b, biasg, (float*)d_out);
}

// Round 11
// 1592.690 us; speedup vs baseline: 1.3437x; 1.0008x over previous
//
#include <hip/hip_runtime.h>

#define B_ 64
#define L_ 2048
#define D_ 128
#define LP 2056   // padded rows per batch (3 left, 5 right incl. alignment)
#define PAD 3     // SAME-pad left for W=8

typedef __attribute__((ext_vector_type(8))) short short8;
typedef __attribute__((ext_vector_type(4))) float f32x4;
typedef __attribute__((ext_vector_type(4))) unsigned short us4;

static __device__ __forceinline__ float bf2f(unsigned short u) {
  return __uint_as_float(((unsigned int)u) << 16);
}
static __device__ __forceinline__ unsigned short f2bf(float f) {
  unsigned int x = __float_as_uint(f);
  unsigned int r = (x + 0x7fffu + ((x >> 16) & 1u)) >> 16;  // RNE
  return (unsigned short)r;
}

// ---------------------------------------------------------------------------
// K0: gather tok -> bf16 padded [B,LP,128]; gather bias; transpose weights.
// ---------------------------------------------------------------------------
__global__ __launch_bounds__(256) void k_prep(
    const int* __restrict__ code, const float* __restrict__ E,
    const float* __restrict__ bias_table, const float* __restrict__ Wx,
    const float* __restrict__ c1w, const float* __restrict__ c2w,
    unsigned short* __restrict__ tokpad,
    unsigned short* __restrict__ WxT, unsigned short* __restrict__ c1wT,
    unsigned short* __restrict__ c2wT, float* __restrict__ biasg)
{
  int id = blockIdx.x * 256 + threadIdx.x;
  const int N0 = B_ * LP * 16;            // tokpad in uint4 (8 bf16) chunks
  if (id < N0) {
    int b = id / (LP * 16); int rem = id % (LP * 16);
    int row = rem >> 4, c8 = rem & 15;
    uint4 o = {0u,0u,0u,0u};
    if (row >= PAD && row < PAD + L_) {
      int cd = code[b * L_ + (row - PAD)];
      const float4* e = (const float4*)(E + (size_t)cd * D_ + c8 * 8);
      float4 e0 = e[0], e1 = e[1];
      o.x = f2bf(e0.x) | ((unsigned int)f2bf(e0.y) << 16);
      o.y = f2bf(e0.z) | ((unsigned int)f2bf(e0.w) << 16);
      o.z = f2bf(e1.x) | ((unsigned int)f2bf(e1.y) << 16);
      o.w = f2bf(e1.z) | ((unsigned int)f2bf(e1.w) << 16);
    }
    ((uint4*)tokpad)[id] = o;
    return;
  }
  id -= N0;
  const int N2 = B_ * L_;
  if (id < N2) { biasg[id] = bias_table[code[id]]; return; }
  id -= N2;
  const int N3 = 192 * 128;               // WxT[c][d]
  if (id < N3) { int c = id >> 7, d = id & 127; WxT[id] = f2bf(Wx[d * 192 + c]); return; }
  id -= N3;
  const int N4 = 8 * 64 * 128;            // c1wT[w][c][d]
  if (id < N4) {
    int w = id >> 13, c = (id >> 7) & 63, d = id & 127;
    c1wT[id] = f2bf(c1w[(w * 128 + d) * 64 + c]); return;
  }
  id -= N4;
  const int N5 = 8 * 64 * 64;             // c2wT[w][c][d]
  if (id < N5) {
    int w = id >> 12, c = (id >> 6) & 63, d = id & 63;
    c2wT[id] = f2bf(c2w[(w * 64 + d) * 64 + c]);
  }
}

// ---------------------------------------------------------------------------
// K1: x_proj = tok @ Wx + b_gru[0] -> bf16 TRANSPOSED [B,192,L].
// R10: C tiles bounce through LDS (reusing Bt, same 192x136 shape) so the
// global store is 256 B-contiguous per row — the old direct store scattered
// 8 B pieces at 4 KB stride (6.3M L2 write ops for 50 MB). Values/rounding
// identical: same acc, same f2bf, different store order only.
// ---------------------------------------------------------------------------
__global__ __launch_bounds__(256) void k_xproj(
    const unsigned short* __restrict__ tokpad, const unsigned short* __restrict__ WxT,
    const float* __restrict__ bg, unsigned short* __restrict__ xprojT)
{
  __shared__ __align__(16) unsigned short At[128 * 136];
  __shared__ __align__(16) unsigned short Bt[192 * 136];
  int b = blockIdx.x >> 4;
  int l0 = (blockIdx.x & 15) << 7;
  int tid = threadIdx.x;
  for (int i = tid; i < 128 * 16; i += 256) {
    int row = i >> 4, c8 = i & 15;
    uint4 v = ((const uint4*)tokpad)[(b * LP + PAD + l0 + row) * 16 + c8];
    *((uint4*)&At[row * 136 + c8 * 8]) = v;
  }
  for (int i = tid; i < 192 * 16; i += 256) {
    int row = i >> 4, c8 = i & 15;
    uint4 v = ((const uint4*)WxT)[i];
    *((uint4*)&Bt[row * 136 + c8 * 8]) = v;
  }
  __syncthreads();
  int wave = tid >> 6, lane = tid & 63;
  int m = lane & 15, q = lane >> 4;
  f32x4 acc[2][12];
  #pragma unroll
  for (int mt = 0; mt < 2; ++mt)
    #pragma unroll
    for (int nt = 0; nt < 12; ++nt) acc[mt][nt] = (f32x4){0.f,0.f,0.f,0.f};
  #pragma unroll
  for (int ks = 0; ks < 4; ++ks) {
    int kof = ks * 32 + q * 8;
    short8 a[2], bb[12];
    #pragma unroll
    for (int mt = 0; mt < 2; ++mt)
      a[mt] = *(const short8*)&At[(wave * 32 + mt * 16 + m) * 136 + kof];
    #pragma unroll
    for (int nt = 0; nt < 12; ++nt)
      bb[nt] = *(const short8*)&Bt[(nt * 16 + m) * 136 + kof];
    #pragma unroll
    for (int mt = 0; mt < 2; ++mt)
      #pragma unroll
      for (int nt = 0; nt < 12; ++nt)
        acc[mt][nt] = __builtin_amdgcn_mfma_f32_16x16x32_bf16(a[mt], bb[nt], acc[mt][nt], 0, 0, 0);
  }
  __syncthreads();                        // all MFMA reads of Bt done
  // deposit C (+bias, bf16) transposed into Bt[c][l]  (l = 0..127)
  #pragma unroll
  for (int mt = 0; mt < 2; ++mt) {
    int lrow = wave * 32 + mt * 16 + q * 4;
    #pragma unroll
    for (int nt = 0; nt < 12; ++nt) {
      int c = nt * 16 + m;                 // C col = lane&15
      float b0 = bg[c];
      us4 val;
      val.x = f2bf(acc[mt][nt][0] + b0);
      val.y = f2bf(acc[mt][nt][1] + b0);
      val.z = f2bf(acc[mt][nt][2] + b0);
      val.w = f2bf(acc[mt][nt][3] + b0);
      *((us4*)&Bt[c * 136 + lrow]) = val;
    }
  }
  __syncthreads();
  // coalesced write-out: 16 lanes x 16 B = 256 B contiguous per c-row
  for (int i = tid; i < 192 * 16; i += 256) {
    int row = i >> 4, c8 = i & 15;
    uint4 v = *((const uint4*)&Bt[row * 136 + c8 * 8]);
    ((uint4*)&xprojT[((size_t)b * 192 + row) * L_ + l0])[c8] = v;
  }
}

// ---------------------------------------------------------------------------
// K2 (fused): blocks 0..63 = R6 GRU scan; blocks 64..255 = conv1+conv2 with
// halo recompute (l1 LDS-only, identical bf16 rounding). No cross-block deps.
// ---------------------------------------------------------------------------
#define BARRIER() asm volatile("s_waitcnt lgkmcnt(0)\n\ts_barrier" ::: "memory")

__global__ __launch_bounds__(192)
__attribute__((amdgpu_waves_per_eu(1, 1)))
void k_fused(
    const unsigned short* __restrict__ xprojT, const float* __restrict__ Wh,
    const float* __restrict__ bg, float* __restrict__ h_t,
    const unsigned short* __restrict__ tokpad,
    const unsigned short* __restrict__ c1wT, const float* __restrict__ c1b,
    const unsigned short* __restrict__ c2wT, const float* __restrict__ c2b,
    unsigned short* __restrict__ c2o)
{
  __shared__ __align__(16) unsigned short pool[39744];
  int bid = blockIdx.x;
  int tid = threadIdx.x;

  if (bid < 64) {
    // ================= GRU scan (R6 structure, verbatim) =================
    float* h_lds = (float*)pool;
    float* s_z   = (float*)pool + 64;
    float* s_r   = (float*)pool + 128;

    int b = bid;
    int wave = tid >> 6, j = tid & 63;
    int o = wave * 64 + j;                // output column 0..191

#define DECL_W(i) float4 w##i = {Wh[(4*i+0)*192+o], Wh[(4*i+1)*192+o], \
                                 Wh[(4*i+2)*192+o], Wh[(4*i+3)*192+o]};
    DECL_W(0)  DECL_W(1)  DECL_W(2)  DECL_W(3)
    DECL_W(4)  DECL_W(5)  DECL_W(6)  DECL_W(7)
    DECL_W(8)  DECL_W(9)  DECL_W(10) DECL_W(11)
    DECL_W(12) DECL_W(13) DECL_W(14) DECL_W(15)
#undef DECL_W
#define OPAQ(i) asm volatile("" : "+v"(w##i.x), "+v"(w##i.y), "+v"(w##i.z), "+v"(w##i.w));
    OPAQ(0)  OPAQ(1)  OPAQ(2)  OPAQ(3)
    OPAQ(4)  OPAQ(5)  OPAQ(6)  OPAQ(7)
    OPAQ(8)  OPAQ(9)  OPAQ(10) OPAQ(11)
    OPAQ(12) OPAQ(13) OPAQ(14) OPAQ(15)
#undef OPAQ
    float bias = bg[192 + o];             // b_gru[1][o]

    if (wave == 2) h_lds[j] = 0.f;
    float h_old = 0.f;

    const unsigned short* xc = xprojT + ((size_t)b * 192 + o) * L_;
    const float4* hl4 = (const float4*)h_lds;

    uint4 cur0 = ((const uint4*)xc)[0];
    uint4 cur1 = ((const uint4*)xc)[1];

#define STEP(XU) { \
    BARRIER(); \
    float a0 = bias, a1 = 0.f, a2 = 0.f, a3 = 0.f; \
    { float4 h4; \
      h4 = hl4[0];  a0 = fmaf(h4.x, w0.x, a0);  a1 = fmaf(h4.y, w0.y, a1);  a2 = fmaf(h4.z, w0.z, a2);  a3 = fmaf(h4.w, w0.w, a3); \
      h4 = hl4[1];  a0 = fmaf(h4.x, w1.x, a0);  a1 = fmaf(h4.y, w1.y, a1);  a2 = fmaf(h4.z, w1.z, a2);  a3 = fmaf(h4.w, w1.w, a3); \
      h4 = hl4[2];  a0 = fmaf(h4.x, w2.x, a0);  a1 = fmaf(h4.y, w2.y, a1);  a2 = fmaf(h4.z, w2.z, a2);  a3 = fmaf(h4.w, w2.w, a3); \
      h4 = hl4[3];  a0 = fmaf(h4.x, w3.x, a0);  a1 = fmaf(h4.y, w3.y, a1);  a2 = fmaf(h4.z, w3.z, a2);  a3 = fmaf(h4.w, w3.w, a3); \
      h4 = hl4[4];  a0 = fmaf(h4.x, w4.x, a0);  a1 = fmaf(h4.y, w4.y, a1);  a2 = fmaf(h4.z, w4.z, a2);  a3 = fmaf(h4.w, w4.w, a3); \
      h4 = hl4[5];  a0 = fmaf(h4.x, w5.x, a0);  a1 = fmaf(h4.y, w5.y, a1);  a2 = fmaf(h4.z, w5.z, a2);  a3 = fmaf(h4.w, w5.w, a3); \
      h4 = hl4[6];  a0 = fmaf(h4.x, w6.x, a0);  a1 = fmaf(h4.y, w6.y, a1);  a2 = fmaf(h4.z, w6.z, a2);  a3 = fmaf(h4.w, w6.w, a3); \
      h4 = hl4[7];  a0 = fmaf(h4.x, w7.x, a0);  a1 = fmaf(h4.y, w7.y, a1);  a2 = fmaf(h4.z, w7.z, a2);  a3 = fmaf(h4.w, w7.w, a3); \
      h4 = hl4[8];  a0 = fmaf(h4.x, w8.x, a0);  a1 = fmaf(h4.y, w8.y, a1);  a2 = fmaf(h4.z, w8.z, a2);  a3 = fmaf(h4.w, w8.w, a3); \
      h4 = hl4[9];  a0 = fmaf(h4.x, w9.x, a0);  a1 = fmaf(h4.y, w9.y, a1);  a2 = fmaf(h4.z, w9.z, a2);  a3 = fmaf(h4.w, w9.w, a3); \
      h4 = hl4[10]; a0 = fmaf(h4.x, w10.x, a0); a1 = fmaf(h4.y, w10.y, a1); a2 = fmaf(h4.z, w10.z, a2); a3 = fmaf(h4.w, w10.w, a3); \
      h4 = hl4[11]; a0 = fmaf(h4.x, w11.x, a0); a1 = fmaf(h4.y, w11.y, a1); a2 = fmaf(h4.z, w11.z, a2); a3 = fmaf(h4.w, w11.w, a3); \
      h4 = hl4[12]; a0 = fmaf(h4.x, w12.x, a0); a1 = fmaf(h4.y, w12.y, a1); a2 = fmaf(h4.z, w12.z, a2); a3 = fmaf(h4.w, w12.w, a3); \
      h4 = hl4[13]; a0 = fmaf(h4.x, w13.x, a0); a1 = fmaf(h4.y, w13.y, a1); a2 = fmaf(h4.z, w13.z, a2); a3 = fmaf(h4.w, w13.w, a3); \
      h4 = hl4[14]; a0 = fmaf(h4.x, w14.x, a0); a1 = fmaf(h4.y, w14.y, a1); a2 = fmaf(h4.z, w14.z, a2); a3 = fmaf(h4.w, w14.w, a3); \
      h4 = hl4[15]; a0 = fmaf(h4.x, w15.x, a0); a1 = fmaf(h4.y, w15.y, a1); a2 = fmaf(h4.z, w15.z, a2); a3 = fmaf(h4.w, w15.w, a3); } \
    float s = (a0 + a1) + (a2 + a3); \
    float xv = bf2f((unsigned short)(XU)); \
    if (wave == 0)      s_z[j] = 1.f / (1.f + __expf(-(xv + s))); \
    else if (wave == 1) s_r[j] = 1.f / (1.f + __expf(-(xv + s))); \
    BARRIER(); \
    if (wave == 2) { \
      float z = s_z[j], r = s_r[j]; \
      float e2 = __expf(-2.f * (xv + r * s)); \
      float hh = fmaf(2.f, __frcp_rn(1.f + e2), -1.f); \
      h_old = z * h_old + (1.f - z) * hh; \
      h_lds[j] = h_old; \
    } }

#define STEP8(C) \
    STEP(C.x & 0xffffu) STEP(C.x >> 16) \
    STEP(C.y & 0xffffu) STEP(C.y >> 16) \
    STEP(C.z & 0xffffu) STEP(C.z >> 16) \
    STEP(C.w & 0xffffu) STEP(C.w >> 16)

    for (int t0 = 0; t0 < L_; t0 += 16) {
      int tn = (t0 + 16 < L_) ? t0 + 16 : t0;
      const uint4* pn = (const uint4*)(xc + tn);
      uint4 nxt0 = pn[0];
      uint4 nxt1 = pn[1];
      STEP8(cur0)
      STEP8(cur1)
      cur0 = nxt0; cur1 = nxt1;
    }
#undef STEP8
#undef STEP
    if (wave == 2) h_t[b * 64 + j] = h_old;
    return;
  }

  // ================= fused conv1+conv2 (halo recompute) =================
  unsigned short* At    = pool;           // 152 x 136 shorts = 41344 B
  unsigned short* l1buf = pool + 20672;   // 144 x 72  shorts = 20736 B
  unsigned short* Bw    = pool + 31040;   //  64 x 136 shorts = 17408 B
  int wv = tid >> 6, lane = tid & 63;
  int m = lane & 15, q = lane >> 4;

  for (int job = bid - 64; job < 1024; job += 192) {
    int b = job >> 4;
    int l0 = (job & 15) << 7;
    __syncthreads();                      // prev job fully consumed
    for (int i = tid; i < 152 * 16; i += 192) {
      int row = i >> 4, c8 = i & 15;
      int p = l0 - 3 + row;
      p = p < 0 ? 0 : (p > 2055 ? 2055 : p);
      *((uint4*)&At[row * 136 + c8 * 8]) = ((const uint4*)tokpad)[(b * LP + p) * 16 + c8];
    }
    // ---- conv1: l1 rows [l0-3, l0+140] (9 M-tiles of 16), K=128 ----
    f32x4 acc[3][4];
    #pragma unroll
    for (int mt = 0; mt < 3; ++mt)
      #pragma unroll
      for (int nt = 0; nt < 4; ++nt) acc[mt][nt] = (f32x4){0.f,0.f,0.f,0.f};
    for (int w8 = 0; w8 < 8; ++w8) {
      __syncthreads();
      for (int i = tid; i < 64 * 16; i += 192) {
        int row = i >> 4, c8 = i & 15;
        *((uint4*)&Bw[row * 136 + c8 * 8]) = ((const uint4*)c1wT)[(w8 * 64 + row) * 16 + c8];
      }
      __syncthreads();
      #pragma unroll
      for (int ks = 0; ks < 4; ++ks) {
        int kof = ks * 32 + q * 8;
        short8 a[3], bb[4];
        #pragma unroll
        for (int mt = 0; mt < 3; ++mt) {
          int tl = wv + 3 * mt;
          a[mt] = *(const short8*)&At[(tl * 16 + m + w8) * 136 + kof];
        }
        #pragma unroll
        for (int nt = 0; nt < 4; ++nt)
          bb[nt] = *(const short8*)&Bw[(nt * 16 + m) * 136 + kof];
        #pragma unroll
        for (int mt = 0; mt < 3; ++mt)
          #pragma unroll
          for (int nt = 0; nt < 4; ++nt)
            acc[mt][nt] = __builtin_amdgcn_mfma_f32_16x16x32_bf16(a[mt], bb[nt], acc[mt][nt], 0, 0, 0);
      }
    }
    #pragma unroll
    for (int mt = 0; mt < 3; ++mt) {
      int tl = wv + 3 * mt;
      #pragma unroll
      for (int nt = 0; nt < 4; ++nt) {
        int c = nt * 16 + m;
        float bs = c1b[c];
        #pragma unroll
        for (int r = 0; r < 4; ++r) {
          float v = fmaxf(acc[mt][nt][r] + bs, 0.f);
          l1buf[(tl * 16 + q * 4 + r) * 72 + c] = f2bf(v);
        }
      }
    }
    __syncthreads();
    for (int i2 = tid; i2 < 135 * 8; i2 += 192) {
      int i = i2 >> 3, c8 = i2 & 7;
      int jrow = l0 - 3 + i;
      if (jrow < 0 || jrow > 2047) {
        uint4 z4 = {0u,0u,0u,0u};
        *((uint4*)&l1buf[i * 72 + c8 * 8]) = z4;
      }
    }
    // ---- conv2: out rows [l0, l0+127] (8 M-tiles), K=64 ----
    f32x4 acc2[3][4];
    #pragma unroll
    for (int mt = 0; mt < 3; ++mt)
      #pragma unroll
      for (int nt = 0; nt < 4; ++nt) acc2[mt][nt] = (f32x4){0.f,0.f,0.f,0.f};
    for (int w8 = 0; w8 < 8; ++w8) {
      __syncthreads();
      for (int i = tid; i < 64 * 8; i += 192) {
        int row = i >> 3, c8 = i & 7;
        *((uint4*)&Bw[row * 72 + c8 * 8]) = ((const uint4*)c2wT)[(w8 * 64 + row) * 8 + c8];
      }
      __syncthreads();
      #pragma unroll
      for (int ks = 0; ks < 2; ++ks) {
        int kof = ks * 32 + q * 8;
        short8 a[3], bb[4];
        #pragma unroll
        for (int mt = 0; mt < 3; ++mt) {
          int tl = wv + 3 * mt;
          if (tl < 8)
            a[mt] = *(const short8*)&l1buf[(tl * 16 + m + w8) * 72 + kof];
        }
        #pragma unroll
        for (int nt = 0; nt < 4; ++nt)
          bb[nt] = *(const short8*)&Bw[(nt * 16 + m) * 72 + kof];
        #pragma unroll
        for (int mt = 0; mt < 3; ++mt) {
          int tl = wv + 3 * mt;
          if (tl < 8)
            #pragma unroll
            for (int nt = 0; nt < 4; ++nt)
              acc2[mt][nt] = __builtin_amdgcn_mfma_f32_16x16x32_bf16(a[mt], bb[nt], acc2[mt][nt], 0, 0, 0);
        }
      }
    }
    #pragma unroll
    for (int mt = 0; mt < 3; ++mt) {
      int tl = wv + 3 * mt;
      if (tl < 8) {
        #pragma unroll
        for (int nt = 0; nt < 4; ++nt) {
          int c = nt * 16 + m;
          float bs = c2b[c];
          #pragma unroll
          for (int r = 0; r < 4; ++r)
            c2o[(size_t)(b * L_ + l0 + tl * 16 + q * 4 + r) * 64 + c] = f2bf(acc2[mt][nt][r] + bs);
        }
      }
    }
  }
}

// ---------------------------------------------------------------------------
// K5: per-batch tail: L2=c2o*h_t -> l2norm -> conv3 -> softmax alpha ->
//     n_hat = sum alpha*tok -> logits = tok.n_hat + bias -> softmax -> out
// ---------------------------------------------------------------------------
__global__ __launch_bounds__(256) void k_final(
    const unsigned short* __restrict__ tokpad, const unsigned short* __restrict__ c2o,
    const float* __restrict__ h_t, const float* __restrict__ c3w,
    const float* __restrict__ c3b, const float* __restrict__ biasg,
    float* __restrict__ out)
{
  __shared__ float Lf[71 * 65];
  __shared__ float a_lds[2048];
  __shared__ float l_lds[2048];
  __shared__ float red[256];
  __shared__ float nred[512];
  __shared__ float nhat[128];
  __shared__ float ht[64];
  __shared__ float c3[512];
  int b = blockIdx.x, tid = threadIdx.x, lane = tid & 63, wave = tid >> 6;
  if (tid < 64) ht[tid] = h_t[b * 64 + tid];
  for (int i = tid; i < 512; i += 256) c3[i] = c3w[i];
  float c3bias = c3b[0];
  __syncthreads();
  // ---- pass 1: a_logits via normalized features + conv3 (tiles of 64 l) ----
  for (int tile = 0; tile < 32; ++tile) {
    int lt = tile << 6;
    for (int i0 = wave; i0 < 71; i0 += 4) {
      int l = lt - 3 + i0;
      float v = 0.f;
      if (l >= 0 && l < L_) v = bf2f(c2o[((size_t)b * L_ + l) * 64 + lane]) * ht[lane];
      float ss = v * v;
      #pragma unroll
      for (int msk = 1; msk < 64; msk <<= 1) ss += __shfl_xor(ss, msk);
      Lf[i0 * 65 + lane] = v * rsqrtf(ss + 1e-12f);
    }
    __syncthreads();
    {
      int u = lane, part = wave;
      float p = 0.f;
      #pragma unroll
      for (int w = 0; w < 8; ++w)
        #pragma unroll
        for (int cc = 0; cc < 16; ++cc) {
          int c = part * 16 + cc;
          p += Lf[(u + w) * 65 + c] * c3[w * 64 + c];
        }
      red[tid] = p;
    }
    __syncthreads();
    if (tid < 64) a_lds[lt + tid] = red[tid] + red[64 + tid] + red[128 + tid] + red[192 + tid] + c3bias;
    __syncthreads();
  }
  // ---- pass 2: softmax alpha over 2048 ----
  {
    float mx = -1e30f;
    for (int i = tid; i < 2048; i += 256) mx = fmaxf(mx, a_lds[i]);
    #pragma unroll
    for (int msk = 1; msk < 64; msk <<= 1) mx = fmaxf(mx, __shfl_xor(mx, msk));
    if (lane == 0) red[wave] = mx;
    __syncthreads();
    mx = fmaxf(fmaxf(red[0], red[1]), fmaxf(red[2], red[3]));
    float sm = 0.f;
    for (int i = tid; i < 2048; i += 256) sm += __expf(a_lds[i] - mx);
    #pragma unroll
    for (int msk = 1; msk < 64; msk <<= 1) sm += __shfl_xor(sm, msk);
    __syncthreads();
    if (lane == 0) red[wave] = sm;
    __syncthreads();
    sm = red[0] + red[1] + red[2] + red[3];
    float inv = 1.f / sm;
    for (int i = tid; i < 2048; i += 256) a_lds[i] = __expf(a_lds[i] - mx) * inv;
    __syncthreads();
  }
  // ---- pass 3: n_hat[128] = sum_l alpha_l * tok[l][:] ----
  {
    int d2 = tid & 63, g = tid >> 6;
    float ax = 0.f, ay = 0.f;
    for (int l = g; l < L_; l += 4) {
      unsigned int uu = *(const unsigned int*)&tokpad[((size_t)b * LP + PAD + l) * 128 + d2 * 2];
      float al = a_lds[l];
      ax += al * bf2f((unsigned short)(uu & 0xffffu));
      ay += al * bf2f((unsigned short)(uu >> 16));
    }
    nred[g * 128 + d2 * 2] = ax;
    nred[g * 128 + d2 * 2 + 1] = ay;
    __syncthreads();
    if (tid < 128) nhat[tid] = nred[tid] + nred[128 + tid] + nred[256 + tid] + nred[384 + tid];
    __syncthreads();
  }
  // ---- pass 4: logits = tok . n_hat + bias ----
  for (int li = 0; li < 8; ++li) {
    int l = li * 256 + tid;
    const uint4* rowp = (const uint4*)&tokpad[((size_t)b * LP + PAD + l) * 128];
    float s = 0.f;
    #pragma unroll
    for (int jj = 0; jj < 16; ++jj) {
      uint4 uu = rowp[jj];
      s += bf2f((unsigned short)(uu.x & 0xffffu)) * nhat[jj*8+0]
         + bf2f((unsigned short)(uu.x >> 16))     * nhat[jj*8+1]
         + bf2f((unsigned short)(uu.y & 0xffffu)) * nhat[jj*8+2]
         + bf2f((unsigned short)(uu.y >> 16))     * nhat[jj*8+3]
         + bf2f((unsigned short)(uu.z & 0xffffu)) * nhat[jj*8+4]
         + bf2f((unsigned short)(uu.z >> 16))     * nhat[jj*8+5]
         + bf2f((unsigned short)(uu.w & 0xffffu)) * nhat[jj*8+6]
         + bf2f((unsigned short)(uu.w >> 16))     * nhat[jj*8+7];
    }
    l_lds[l] = s + biasg[b * L_ + l];
  }
  __syncthreads();
  // ---- pass 5: final softmax -> out ----
  {
    float mx = -1e30f;
    for (int i = tid; i < 2048; i += 256) mx = fmaxf(mx, l_lds[i]);
    #pragma unroll
    for (int msk = 1; msk < 64; msk <<= 1) mx = fmaxf(mx, __shfl_xor(mx, msk));
    __syncthreads();
    if (lane == 0) red[wave] = mx;
    __syncthreads();
    mx = fmaxf(fmaxf(red[0], red[1]), fmaxf(red[2], red[3]));
    float sm = 0.f;
    for (int i = tid; i < 2048; i += 256) sm += __expf(l_lds[i] - mx);
    #pragma unroll
    for (int msk = 1; msk < 64; msk <<= 1) sm += __shfl_xor(sm, msk);
    __syncthreads();
    if (lane == 0) red[wave] = sm;
    __syncthreads();
    sm = red[0] + red[1] + red[2] + red[3];
    float inv = 1.f / sm;
    for (int i = tid; i < 2048; i += 256) out[b * L_ + i] = __expf(l_lds[i] - mx) * inv;
  }
}

// ---------------------------------------------------------------------------
extern "C" void kernel_launch(void* const* d_in, const int* in_sizes, int n_in,
                              void* d_out, int out_size, void* d_ws, size_t ws_size,
                              hipStream_t stream) {
  const int*   code = (const int*)d_in[0];
  const float* E    = (const float*)d_in[1];
  const float* bt   = (const float*)d_in[2];
  const float* Wx   = (const float*)d_in[3];
  const float* Wh   = (const float*)d_in[4];
  const float* bg   = (const float*)d_in[5];
  const float* c1w  = (const float*)d_in[6];
  const float* c1b  = (const float*)d_in[7];
  const float* c2w  = (const float*)d_in[8];
  const float* c2b  = (const float*)d_in[9];
  const float* c3w  = (const float*)d_in[10];
  const float* c3b  = (const float*)d_in[11];
  char* ws = (char*)d_ws;
  unsigned short* tokpad = (unsigned short*)(ws);               // 33,685,504 B
  unsigned short* xprojT = (unsigned short*)(ws + 50528256);    // 50,331,648 B
  unsigned short* c2o    = (unsigned short*)(ws + 100859904);   // 16,777,216 B
  unsigned short* WxT    = (unsigned short*)(ws + 117637120);   //     49,152 B
  unsigned short* c1wT   = (unsigned short*)(ws + 117686272);   //    131,072 B
  unsigned short* c2wT   = (unsigned short*)(ws + 117817344);   //     65,536 B
  float*          htp    = (float*)(ws + 117882880);            //     16,384 B
  float*          biasg  = (float*)(ws + 117899264);            //    524,288 B
  // total ws use: 118,423,552 B

  k_prep <<<9216, 256, 0, stream>>>(code, E, bt, Wx, c1w, c2w, tokpad, WxT, c1wT, c2wT, biasg);
  k_xproj<<<1024, 256, 0, stream>>>(tokpad, WxT, bg, xprojT);
  k_fused<<<256, 192, 0, stream>>>(xprojT, Wh, bg, htp, tokpad, c1wT, c1b, c2wT, c2b, c2o);
  k_final<<<64, 256, 0, stream>>>(tokpad, c2o, htp, c3w, c3b, biasg, (float*)d_out);
}